// Round 1
// baseline (971.124 us; speedup 1.0000x reference)
//
#include <hip/hip_runtime.h>
#include <hip/hip_bf16.h>

// ---------------------------------------------------------------------------
// GCN graph classifier: 2x GCNConv(128->128) + global_mean_pool + Linear(128->2)
// Strategy: build CSR by destination once per call (histogram/scan/fill),
// pull-style aggregation (wave per node, no atomics on message stream),
// f32 GEMM with W staged in LDS.
// ---------------------------------------------------------------------------

#define HDIM 128

// K1: weighted in-degree + edge count per destination
__global__ __launch_bounds__(256) void deg_count_kernel(
    const int* __restrict__ col, const float* __restrict__ ew,
    float* __restrict__ deg, int* __restrict__ cnt, int E) {
  int e = blockIdx.x * 256 + threadIdx.x;
  if (e < E) {
    int c = col[e];
    atomicAdd(&deg[c], ew[e]);
    atomicAdd(&cnt[c], 1);
  }
}

// K2: dis = rsqrt(deg + 1) (self-loop weight 1); also per-graph node counts
__global__ __launch_bounds__(256) void dis_gcnt_kernel(
    float* __restrict__ deg_dis, const int* __restrict__ batch,
    float* __restrict__ gcnt, int n) {
  int i = blockIdx.x * 256 + threadIdx.x;
  if (i < n) {
    deg_dis[i] = rsqrtf(deg_dis[i] + 1.0f);
    atomicAdd(&gcnt[batch[i]], 1.0f);
  }
}

// K3a: per-block exclusive scan (256 elems/block) + block sums
__global__ __launch_bounds__(256) void scan_block_kernel(
    const int* __restrict__ in, int* __restrict__ out, int* __restrict__ part, int n) {
  __shared__ int tmp[256];
  int tid = threadIdx.x;
  int i = blockIdx.x * 256 + tid;
  int v = (i < n) ? in[i] : 0;
  tmp[tid] = v;
  __syncthreads();
  for (int d = 1; d < 256; d <<= 1) {
    int t = (tid >= d) ? tmp[tid - d] : 0;
    __syncthreads();
    tmp[tid] += t;
    __syncthreads();
  }
  if (i < n) out[i] = tmp[tid] - v;       // exclusive
  if (tid == 255) part[blockIdx.x] = tmp[255];
}

// K3b: scan the block sums (single block, nb <= 512)
__global__ __launch_bounds__(512) void scan_part_kernel(int* part, int nb) {
  __shared__ int tmp[512];
  int tid = threadIdx.x;
  int v = (tid < nb) ? part[tid] : 0;
  tmp[tid] = v;
  __syncthreads();
  for (int d = 1; d < 512; d <<= 1) {
    int t = (tid >= d) ? tmp[tid - d] : 0;
    __syncthreads();
    tmp[tid] += t;
    __syncthreads();
  }
  if (tid < nb) part[tid] = tmp[tid] - v; // exclusive
}

// K3c: add block offsets; write sentinel off[n] = E
__global__ __launch_bounds__(256) void scan_add_kernel(
    int* __restrict__ off, const int* __restrict__ part, int n, int total) {
  int i = blockIdx.x * 256 + threadIdx.x;
  if (i < n) off[i] += part[blockIdx.x];
  if (i == 0) off[n] = total;
}

// K4: fill CSR; pre-gather source row id and dis[row]*ew into CSR order
__global__ __launch_bounds__(256) void csr_fill_kernel(
    const int* __restrict__ row, const int* __restrict__ col,
    const float* __restrict__ ew, const float* __restrict__ dis,
    const int* __restrict__ off, int* __restrict__ cursor,
    int* __restrict__ csr_row, float* __restrict__ csr_nrm, int E) {
  int e = blockIdx.x * 256 + threadIdx.x;
  if (e < E) {
    int c = col[e];
    int slot = off[c] + atomicAdd(&cursor[c], 1);
    int r = row[e];
    csr_row[slot] = r;
    csr_nrm[slot] = dis[r] * ew[e];
  }
}

// GEMM: Y[n][128] = X[n][128] @ W[128][128]; W staged in LDS.
// 4 threads per row, 32 output features per thread.
__global__ __launch_bounds__(256) void gemm128_kernel(
    const float* __restrict__ X, const float* __restrict__ W,
    float* __restrict__ Y, int nrows) {
  __shared__ float Wl[HDIM * HDIM];
  int tid = threadIdx.x;
  for (int i = tid; i < HDIM * HDIM / 4; i += 256)
    ((float4*)Wl)[i] = ((const float4*)W)[i];
  __syncthreads();

  int rl = tid >> 2;
  int f0 = (tid & 3) * 32;
  int r = blockIdx.x * 64 + rl;
  if (r >= nrows) return;

  float acc[32];
#pragma unroll
  for (int j = 0; j < 32; ++j) acc[j] = 0.0f;

  const float* xr = X + (size_t)r * HDIM;
  for (int k = 0; k < HDIM; k += 4) {
    float4 xv = *(const float4*)(xr + k);
#pragma unroll
    for (int kk = 0; kk < 4; ++kk) {
      float xs = (kk == 0) ? xv.x : (kk == 1) ? xv.y : (kk == 2) ? xv.z : xv.w;
      const float* wr = &Wl[(k + kk) * HDIM + f0];
#pragma unroll
      for (int j = 0; j < 32; j += 4) {
        float4 wv = *(const float4*)(wr + j);
        acc[j]     += xs * wv.x;
        acc[j + 1] += xs * wv.y;
        acc[j + 2] += xs * wv.z;
        acc[j + 3] += xs * wv.w;
      }
    }
  }
  float* yr = Y + (size_t)r * HDIM + f0;
#pragma unroll
  for (int j = 0; j < 32; j += 4) {
    float4 v = make_float4(acc[j], acc[j + 1], acc[j + 2], acc[j + 3]);
    *(float4*)(yr + j) = v;
  }
}

// Aggregate (pull): one wave per node; lanes hold 2 features each.
// out[c] = relu( dis[c]^2*xw[c] + sum_e csr_nrm[e]*dis[c]*xw[csr_row[e]] + bias )
__global__ __launch_bounds__(256) void agg_kernel(
    const float* __restrict__ xw, const int* __restrict__ csr_row,
    const float* __restrict__ csr_nrm, const float* __restrict__ dis,
    const int* __restrict__ off, const float* __restrict__ bias,
    float* __restrict__ out, int n) {
  int node = blockIdx.x * 4 + (threadIdx.x >> 6);
  if (node >= n) return;
  int lane = threadIdx.x & 63;
  float dc = dis[node];
  float2 acc;
  {
    float2 xv = *(const float2*)(xw + (size_t)node * HDIM + lane * 2);
    float w = dc * dc;
    acc.x = w * xv.x;
    acc.y = w * xv.y;
  }
  int s = off[node], t = off[node + 1];
  for (int i = s; i < t; ++i) {
    int r = csr_row[i];
    float nrm = csr_nrm[i] * dc;
    float2 xv = *(const float2*)(xw + (size_t)r * HDIM + lane * 2);
    acc.x += nrm * xv.x;
    acc.y += nrm * xv.y;
  }
  float2 b = *(const float2*)(bias + lane * 2);
  acc.x = fmaxf(acc.x + b.x, 0.0f);
  acc.y = fmaxf(acc.y + b.y, 0.0f);
  *(float2*)(out + (size_t)node * HDIM + lane * 2) = acc;
}

// Layer-2 aggregate fused with relu + mean-pool accumulation
__global__ __launch_bounds__(256) void agg_pool_kernel(
    const float* __restrict__ xw, const int* __restrict__ csr_row,
    const float* __restrict__ csr_nrm, const float* __restrict__ dis,
    const int* __restrict__ off, const float* __restrict__ bias,
    const int* __restrict__ batch, float* __restrict__ pooled, int n) {
  int node = blockIdx.x * 4 + (threadIdx.x >> 6);
  if (node >= n) return;
  int lane = threadIdx.x & 63;
  float dc = dis[node];
  float2 acc;
  {
    float2 xv = *(const float2*)(xw + (size_t)node * HDIM + lane * 2);
    float w = dc * dc;
    acc.x = w * xv.x;
    acc.y = w * xv.y;
  }
  int s = off[node], t = off[node + 1];
  for (int i = s; i < t; ++i) {
    int r = csr_row[i];
    float nrm = csr_nrm[i] * dc;
    float2 xv = *(const float2*)(xw + (size_t)r * HDIM + lane * 2);
    acc.x += nrm * xv.x;
    acc.y += nrm * xv.y;
  }
  float2 b = *(const float2*)(bias + lane * 2);
  acc.x = fmaxf(acc.x + b.x, 0.0f);
  acc.y = fmaxf(acc.y + b.y, 0.0f);
  int g = batch[node];
  atomicAdd(&pooled[(size_t)g * HDIM + lane * 2],     acc.x);
  atomicAdd(&pooled[(size_t)g * HDIM + lane * 2 + 1], acc.y);
}

// Final: out[g][o] = dot(pooled[g]/max(cnt,1), Wl[:,o]) + bl[o]
__global__ __launch_bounds__(64) void final_kernel(
    const float* __restrict__ pooled, const float* __restrict__ gcnt,
    const float* __restrict__ Wl, const float* __restrict__ bl,
    float* __restrict__ out) {
  int g = blockIdx.x;
  int lane = threadIdx.x;
  float inv = 1.0f / fmaxf(gcnt[g], 1.0f);
  float p0 = pooled[g * HDIM + lane] * inv;
  float p1 = pooled[g * HDIM + 64 + lane] * inv;
#pragma unroll
  for (int o = 0; o < 2; ++o) {
    float s = p0 * Wl[lane * 2 + o] + p1 * Wl[(64 + lane) * 2 + o];
    for (int d = 32; d > 0; d >>= 1) s += __shfl_down(s, d);
    if (lane == 0) out[g * 2 + o] = s + bl[o];
  }
}

extern "C" void kernel_launch(void* const* d_in, const int* in_sizes, int n_in,
                              void* d_out, int out_size, void* d_ws, size_t ws_size,
                              hipStream_t stream) {
  const float* x     = (const float*)d_in[0];
  const int*   ei    = (const int*)d_in[1];
  const float* ew    = (const float*)d_in[2];
  const int*   batch = (const int*)d_in[3];
  const float* W1    = (const float*)d_in[4];
  const float* b1    = (const float*)d_in[5];
  const float* W2    = (const float*)d_in[6];
  const float* b2    = (const float*)d_in[7];
  const float* Wl    = (const float*)d_in[8];
  const float* bl    = (const float*)d_in[9];
  float* out = (float*)d_out;

  const int N = in_sizes[0] / HDIM;     // 100000
  const int E = in_sizes[2];            // 1600000
  const int G = out_size / 2;           // 512

  const int* row = ei;
  const int* col = ei + E;

  // ---- workspace layout (256B aligned) ----
  auto al = [](size_t v) { return (v + 255) & ~(size_t)255; };
  char* ws = (char*)d_ws;
  size_t o_dis    = 0;                               // f32[N]
  size_t o_cnt    = o_dis    + al((size_t)N * 4);    // i32[N]
  size_t o_cursor = o_cnt    + al((size_t)N * 4);    // i32[N]
  size_t o_gcnt   = o_cursor + al((size_t)N * 4);    // f32[G]
  size_t o_pooled = o_gcnt   + al((size_t)G * 4);    // f32[G*128]
  size_t zero_end = o_pooled + al((size_t)G * HDIM * 4);
  size_t o_off    = zero_end;                        // i32[N+1]
  size_t o_part   = o_off    + al(((size_t)N + 1) * 4); // i32[512]
  size_t o_crow   = o_part   + al(2048);             // i32[E]
  size_t o_cnrm   = o_crow   + al((size_t)E * 4);    // f32[E]
  size_t o_bufA   = o_cnrm   + al((size_t)E * 4);    // f32[N*128]
  size_t o_bufB   = o_bufA   + al((size_t)N * HDIM * 4); // f32[N*128]

  float* dis     = (float*)(ws + o_dis);
  int*   cnt     = (int*)  (ws + o_cnt);
  int*   cursor  = (int*)  (ws + o_cursor);
  float* gcnt    = (float*)(ws + o_gcnt);
  float* pooled  = (float*)(ws + o_pooled);
  int*   off     = (int*)  (ws + o_off);
  int*   part    = (int*)  (ws + o_part);
  int*   csr_row = (int*)  (ws + o_crow);
  float* csr_nrm = (float*)(ws + o_cnrm);
  float* bufA    = (float*)(ws + o_bufA);
  float* bufB    = (float*)(ws + o_bufB);

  // zero accumulators (deg, cnt, cursor, gcnt, pooled) in one memset
  hipMemsetAsync(ws, 0, zero_end, stream);

  int EB = (E + 255) / 256;
  int NB = (N + 255) / 256;

  deg_count_kernel<<<EB, 256, 0, stream>>>(col, ew, dis, cnt, E);
  dis_gcnt_kernel<<<NB, 256, 0, stream>>>(dis, batch, gcnt, N);

  scan_block_kernel<<<NB, 256, 0, stream>>>(cnt, off, part, N);
  scan_part_kernel<<<1, 512, 0, stream>>>(part, NB);
  scan_add_kernel<<<NB, 256, 0, stream>>>(off, part, N, E);

  csr_fill_kernel<<<EB, 256, 0, stream>>>(row, col, ew, dis, off, cursor,
                                          csr_row, csr_nrm, E);

  int GB = (N + 63) / 64;     // gemm blocks
  int AB = (N + 3) / 4;       // agg blocks (4 waves/block)

  // layer 1: xw = x @ W1 ; h1 = relu(agg(xw) + b1)
  gemm128_kernel<<<GB, 256, 0, stream>>>(x, W1, bufA, N);
  agg_kernel<<<AB, 256, 0, stream>>>(bufA, csr_row, csr_nrm, dis, off, b1, bufB, N);

  // layer 2: xw2 = h1 @ W2 ; h2 = relu(agg(xw2) + b2) -> pooled
  gemm128_kernel<<<GB, 256, 0, stream>>>(bufB, W2, bufA, N);
  agg_pool_kernel<<<AB, 256, 0, stream>>>(bufA, csr_row, csr_nrm, dis, off, b2,
                                          batch, pooled, N);

  final_kernel<<<G, 64, 0, stream>>>(pooled, gcnt, Wl, bl, out);
}

// Round 2
// 647.005 us; speedup vs baseline: 1.5010x; 1.5010x over previous
//
#include <hip/hip_runtime.h>
#include <hip/hip_fp16.h>

// ---------------------------------------------------------------------------
// GCN graph classifier: 2x GCNConv(128->128) + global_mean_pool + Linear(128->2)
// R2: fp16 message table (halves gather bytes), packed int2 CSR with norm
// pre-folded (dis[row]*ew*dis[col]), 4x unrolled gather loop for MLP,
// atomic-free segment pooling (batch is sorted).
// ---------------------------------------------------------------------------

#define HDIM 128
typedef unsigned int uint;

// K1: weighted in-degree + edge count per destination
__global__ __launch_bounds__(256) void deg_count_kernel(
    const int* __restrict__ col, const float* __restrict__ ew,
    float* __restrict__ deg, int* __restrict__ cnt, int E) {
  int e = blockIdx.x * 256 + threadIdx.x;
  if (e < E) {
    int c = col[e];
    atomicAdd(&deg[c], ew[e]);
    atomicAdd(&cnt[c], 1);
  }
}

// K2: dis = rsqrt(deg + 1) (self-loop weight 1)
__global__ __launch_bounds__(256) void dis_kernel(float* __restrict__ deg_dis, int n) {
  int i = blockIdx.x * 256 + threadIdx.x;
  if (i < n) deg_dis[i] = rsqrtf(deg_dis[i] + 1.0f);
}

// K2b: graph segment starts from sorted batch ids. start[g] for g in [0,G].
__global__ __launch_bounds__(256) void gstart_kernel(
    const int* __restrict__ batch, int* __restrict__ start, int n, int G) {
  int i = blockIdx.x * 256 + threadIdx.x;
  if (i >= n) return;
  int b = batch[i];
  if (i == 0) {
    for (int h = 0; h <= b; ++h) start[h] = 0;
  } else {
    int bp = batch[i - 1];
    for (int h = bp + 1; h <= b; ++h) start[h] = i;
  }
  if (i == n - 1) {
    for (int h = b + 1; h <= G; ++h) start[h] = n;
  }
}

// K3a: per-block exclusive scan (256 elems/block) + block sums
__global__ __launch_bounds__(256) void scan_block_kernel(
    const int* __restrict__ in, int* __restrict__ out, int* __restrict__ part, int n) {
  __shared__ int tmp[256];
  int tid = threadIdx.x;
  int i = blockIdx.x * 256 + tid;
  int v = (i < n) ? in[i] : 0;
  tmp[tid] = v;
  __syncthreads();
  for (int d = 1; d < 256; d <<= 1) {
    int t = (tid >= d) ? tmp[tid - d] : 0;
    __syncthreads();
    tmp[tid] += t;
    __syncthreads();
  }
  if (i < n) out[i] = tmp[tid] - v;       // exclusive
  if (tid == 255) part[blockIdx.x] = tmp[255];
}

// K3b: scan the block sums (single block, nb <= 512)
__global__ __launch_bounds__(512) void scan_part_kernel(int* part, int nb) {
  __shared__ int tmp[512];
  int tid = threadIdx.x;
  int v = (tid < nb) ? part[tid] : 0;
  tmp[tid] = v;
  __syncthreads();
  for (int d = 1; d < 512; d <<= 1) {
    int t = (tid >= d) ? tmp[tid - d] : 0;
    __syncthreads();
    tmp[tid] += t;
    __syncthreads();
  }
  if (tid < nb) part[tid] = tmp[tid] - v; // exclusive
}

// K3c: add block offsets; write sentinel off[n] = E
__global__ __launch_bounds__(256) void scan_add_kernel(
    int* __restrict__ off, const int* __restrict__ part, int n, int total) {
  int i = blockIdx.x * 256 + threadIdx.x;
  if (i < n) off[i] += part[blockIdx.x];
  if (i == 0) off[n] = total;
}

// K4: fill CSR; pack (src row, dis[row]*ew*dis[col]) as int2
__global__ __launch_bounds__(256) void csr_fill_kernel(
    const int* __restrict__ row, const int* __restrict__ col,
    const float* __restrict__ ew, const float* __restrict__ dis,
    const int* __restrict__ off, int* __restrict__ cursor,
    int2* __restrict__ csr, int E) {
  int e = blockIdx.x * 256 + threadIdx.x;
  if (e < E) {
    int c = col[e];
    int slot = off[c] + atomicAdd(&cursor[c], 1);
    int r = row[e];
    csr[slot] = make_int2(r, __float_as_int(dis[r] * ew[e] * dis[c]));
  }
}

// GEMM: Y[n][128](fp16) = X[n][128](f32) @ W[128][128](f32); W staged in LDS.
// 4 threads per row, 32 output features per thread, fp16 RNE output.
__global__ __launch_bounds__(256) void gemm128_f16_kernel(
    const float* __restrict__ X, const float* __restrict__ W,
    uint* __restrict__ Y, int nrows) {
  __shared__ float Wl[HDIM * HDIM];
  int tid = threadIdx.x;
  for (int i = tid; i < HDIM * HDIM / 4; i += 256)
    ((float4*)Wl)[i] = ((const float4*)W)[i];
  __syncthreads();

  int rl = tid >> 2;
  int f0 = (tid & 3) * 32;
  int r = blockIdx.x * 64 + rl;
  if (r >= nrows) return;

  float acc[32];
#pragma unroll
  for (int j = 0; j < 32; ++j) acc[j] = 0.0f;

  const float* xr = X + (size_t)r * HDIM;
  for (int k = 0; k < HDIM; k += 4) {
    float4 xv = *(const float4*)(xr + k);
#pragma unroll
    for (int kk = 0; kk < 4; ++kk) {
      float xs = (kk == 0) ? xv.x : (kk == 1) ? xv.y : (kk == 2) ? xv.z : xv.w;
      const float* wr = &Wl[(k + kk) * HDIM + f0];
#pragma unroll
      for (int j = 0; j < 32; j += 4) {
        float4 wv = *(const float4*)(wr + j);
        acc[j]     += xs * wv.x;
        acc[j + 1] += xs * wv.y;
        acc[j + 2] += xs * wv.z;
        acc[j + 3] += xs * wv.w;
      }
    }
  }
  uint p[16];
#pragma unroll
  for (int j = 0; j < 32; j += 2) {
    __half2 hp = __floats2half2_rn(acc[j], acc[j + 1]);
    p[j >> 1] = *(uint*)&hp;
  }
  uint* yr = Y + ((size_t)r << 6) + (f0 >> 1);
#pragma unroll
  for (int q = 0; q < 4; ++q)
    ((uint4*)yr)[q] = make_uint4(p[4 * q], p[4 * q + 1], p[4 * q + 2], p[4 * q + 3]);
}

// Aggregate (pull): one wave per node; lanes hold 2 features (one fp16x2 word).
// out[c] = relu( dis[c]^2*xw[c] + sum_e nrm[e]*xw[src[e]] + bias ), f32 out.
__global__ __launch_bounds__(256) void agg_kernel(
    const uint* __restrict__ xw, const int2* __restrict__ csr,
    const float* __restrict__ dis, const int* __restrict__ off,
    const float* __restrict__ bias, float* __restrict__ out, int n) {
  int node = blockIdx.x * 4 + (threadIdx.x >> 6);
  if (node >= n) return;
  int lane = threadIdx.x & 63;
  float dc = dis[node];
  float ax, ay;
  {
    uint v = xw[((size_t)node << 6) + lane];
    float2 f = __half22float2(*(const __half2*)&v);
    float w = dc * dc;
    ax = w * f.x;
    ay = w * f.y;
  }
  int s = off[node], t = off[node + 1];
  for (int i = s; i < t; i += 4) {
    int lim = t - 1;
    int2 e0 = csr[i];
    int2 e1 = csr[min(i + 1, lim)];
    int2 e2 = csr[min(i + 2, lim)];
    int2 e3 = csr[min(i + 3, lim)];
    uint v0 = xw[((size_t)e0.x << 6) + lane];
    uint v1 = xw[((size_t)e1.x << 6) + lane];
    uint v2 = xw[((size_t)e2.x << 6) + lane];
    uint v3 = xw[((size_t)e3.x << 6) + lane];
    float n0 = __int_as_float(e0.y);
    float n1 = (i + 1 < t) ? __int_as_float(e1.y) : 0.0f;
    float n2 = (i + 2 < t) ? __int_as_float(e2.y) : 0.0f;
    float n3 = (i + 3 < t) ? __int_as_float(e3.y) : 0.0f;
    float2 f0 = __half22float2(*(const __half2*)&v0);
    float2 f1 = __half22float2(*(const __half2*)&v1);
    float2 f2 = __half22float2(*(const __half2*)&v2);
    float2 f3 = __half22float2(*(const __half2*)&v3);
    ax += n0 * f0.x; ay += n0 * f0.y;
    ax += n1 * f1.x; ay += n1 * f1.y;
    ax += n2 * f2.x; ay += n2 * f2.y;
    ax += n3 * f3.x; ay += n3 * f3.y;
  }
  float2 b = *(const float2*)(bias + lane * 2);
  ax = fmaxf(ax + b.x, 0.0f);
  ay = fmaxf(ay + b.y, 0.0f);
  *(float2*)(out + ((size_t)node << 7) + lane * 2) = make_float2(ax, ay);
}

// Mean-pool over sorted batch segments: one block per graph, no atomics.
__global__ __launch_bounds__(128) void pool_kernel(
    const float* __restrict__ h, const int* __restrict__ start,
    float* __restrict__ pooled) {
  int g = blockIdx.x;
  int f = threadIdx.x;
  int s = start[g], e = start[g + 1];
  float s0 = 0.0f, s1 = 0.0f;
  int r = s;
  for (; r + 2 <= e; r += 2) {
    s0 += h[(size_t)r * HDIM + f];
    s1 += h[(size_t)(r + 1) * HDIM + f];
  }
  if (r < e) s0 += h[(size_t)r * HDIM + f];
  float inv = 1.0f / (float)max(e - s, 1);
  pooled[g * HDIM + f] = (s0 + s1) * inv;
}

// Final: out[g][o] = dot(pooled[g], Wl[:,o]) + bl[o]
__global__ __launch_bounds__(64) void final_kernel(
    const float* __restrict__ pooled, const float* __restrict__ Wl,
    const float* __restrict__ bl, float* __restrict__ out) {
  int g = blockIdx.x;
  int lane = threadIdx.x;
  float p0 = pooled[g * HDIM + lane];
  float p1 = pooled[g * HDIM + 64 + lane];
#pragma unroll
  for (int o = 0; o < 2; ++o) {
    float s = p0 * Wl[lane * 2 + o] + p1 * Wl[(64 + lane) * 2 + o];
    for (int d = 32; d > 0; d >>= 1) s += __shfl_down(s, d);
    if (lane == 0) out[g * 2 + o] = s + bl[o];
  }
}

extern "C" void kernel_launch(void* const* d_in, const int* in_sizes, int n_in,
                              void* d_out, int out_size, void* d_ws, size_t ws_size,
                              hipStream_t stream) {
  const float* x     = (const float*)d_in[0];
  const int*   ei    = (const int*)d_in[1];
  const float* ew    = (const float*)d_in[2];
  const int*   batch = (const int*)d_in[3];
  const float* W1    = (const float*)d_in[4];
  const float* b1    = (const float*)d_in[5];
  const float* W2    = (const float*)d_in[6];
  const float* b2    = (const float*)d_in[7];
  const float* Wl    = (const float*)d_in[8];
  const float* bl    = (const float*)d_in[9];
  float* out = (float*)d_out;

  const int N = in_sizes[0] / HDIM;     // 100000
  const int E = in_sizes[2];            // 1600000
  const int G = out_size / 2;           // 512

  const int* row = ei;
  const int* col = ei + E;

  // ---- workspace layout (256B aligned) ----
  auto al = [](size_t v) { return (v + 255) & ~(size_t)255; };
  char* ws = (char*)d_ws;
  size_t o_dis    = 0;                                   // f32[N]
  size_t o_cnt    = o_dis    + al((size_t)N * 4);        // i32[N]
  size_t o_cursor = o_cnt    + al((size_t)N * 4);        // i32[N]
  size_t zero_end = o_cursor + al((size_t)N * 4);
  size_t o_start  = zero_end;                            // i32[G+1]
  size_t o_off    = o_start  + al(((size_t)G + 1) * 4);  // i32[N+1]
  size_t o_part   = o_off    + al(((size_t)N + 1) * 4);  // i32[512]
  size_t o_csr    = o_part   + al(2048);                 // int2[E]
  size_t o_xw     = o_csr    + al((size_t)E * 8);        // fp16x2 uint[N*64]
  size_t o_h      = o_xw     + al((size_t)N * 64 * 4);   // f32[N*128]
  size_t o_pooled = o_h      + al((size_t)N * HDIM * 4); // f32[G*128]

  float* dis     = (float*)(ws + o_dis);
  int*   cnt     = (int*)  (ws + o_cnt);
  int*   cursor  = (int*)  (ws + o_cursor);
  int*   start   = (int*)  (ws + o_start);
  int*   off     = (int*)  (ws + o_off);
  int*   part    = (int*)  (ws + o_part);
  int2*  csr     = (int2*) (ws + o_csr);
  uint*  xw      = (uint*) (ws + o_xw);
  float* hbuf    = (float*)(ws + o_h);
  float* pooled  = (float*)(ws + o_pooled);

  // zero accumulators (deg, cnt, cursor)
  hipMemsetAsync(ws, 0, zero_end, stream);

  int EB = (E + 255) / 256;
  int NB = (N + 255) / 256;

  deg_count_kernel<<<EB, 256, 0, stream>>>(col, ew, dis, cnt, E);
  dis_kernel<<<NB, 256, 0, stream>>>(dis, N);
  gstart_kernel<<<NB, 256, 0, stream>>>(batch, start, N, G);

  scan_block_kernel<<<NB, 256, 0, stream>>>(cnt, off, part, N);
  scan_part_kernel<<<1, 512, 0, stream>>>(part, NB);
  scan_add_kernel<<<NB, 256, 0, stream>>>(off, part, N, E);

  csr_fill_kernel<<<EB, 256, 0, stream>>>(row, col, ew, dis, off, cursor, csr, E);

  int GB = (N + 63) / 64;     // gemm blocks
  int AB = (N + 3) / 4;       // agg blocks (4 waves/block)

  // layer 1: xw = fp16(x @ W1) ; h1 = relu(agg(xw) + b1)   (f32)
  gemm128_f16_kernel<<<GB, 256, 0, stream>>>(x, W1, xw, N);
  agg_kernel<<<AB, 256, 0, stream>>>(xw, csr, dis, off, b1, hbuf, N);

  // layer 2: xw2 = fp16(h1 @ W2) ; h2 = relu(agg(xw2) + b2) (f32)
  gemm128_f16_kernel<<<GB, 256, 0, stream>>>(hbuf, W2, xw, N);
  agg_kernel<<<AB, 256, 0, stream>>>(xw, csr, dis, off, b2, hbuf, N);

  // mean-pool per sorted-batch segment, then linear head
  pool_kernel<<<G, 128, 0, stream>>>(hbuf, start, pooled);
  final_kernel<<<G, 64, 0, stream>>>(pooled, Wl, bl, out);
}

// Round 3
// 528.875 us; speedup vs baseline: 1.8362x; 1.2234x over previous
//
#include <hip/hip_runtime.h>
#include <hip/hip_fp16.h>

// ---------------------------------------------------------------------------
// GCN graph classifier: 2x GCNConv(128->128) + global_mean_pool + Linear(128->2)
// R3: single packed 64-bit atomic per edge builds {degree, count, CSR-rank}
// in one pass (count in bits[40:63], ew in 20.20 fixed point in bits[0:39],
// returned old value >> 40 = this edge's rank within its destination).
// CSR fill is then atomic-free. fp16 message table, pull aggregation,
// sorted-batch segment pooling.
// ---------------------------------------------------------------------------

#define HDIM 128
typedef unsigned int uint;
typedef unsigned long long u64;

// K1: one packed atomic per edge; returns rank within destination node.
__global__ __launch_bounds__(256) void hist_kernel(
    const int* __restrict__ col, const float* __restrict__ ew,
    u64* __restrict__ dc64, unsigned short* __restrict__ rank, int E) {
  int e = blockIdx.x * 256 + threadIdx.x;
  if (e < E) {
    int c = col[e];
    u64 pack = ((u64)1 << 40) + (u64)__float2uint_rn(ew[e] * 1048576.0f);
    u64 old = atomicAdd(&dc64[c], pack);
    rank[e] = (unsigned short)(old >> 40);
  }
}

// K2: unpack deg -> dis = rsqrt(deg+1), cnt; graph segment starts (sorted batch)
__global__ __launch_bounds__(256) void node_kernel(
    const u64* __restrict__ dc64, float* __restrict__ dis, int* __restrict__ cnt,
    const int* __restrict__ batch, int* __restrict__ start, int n, int G) {
  int i = blockIdx.x * 256 + threadIdx.x;
  if (i >= n) return;
  u64 v = dc64[i];
  float deg = (float)(v & 0xFFFFFFFFFFull) * (1.0f / 1048576.0f);
  dis[i] = rsqrtf(deg + 1.0f);
  cnt[i] = (int)(v >> 40);
  int b = batch[i];
  if (i == 0) {
    for (int h = 0; h <= b; ++h) start[h] = 0;
  } else {
    int bp = batch[i - 1];
    for (int h = bp + 1; h <= b; ++h) start[h] = i;
  }
  if (i == n - 1) {
    for (int h = b + 1; h <= G; ++h) start[h] = n;
  }
}

// K3a: per-block exclusive scan (256 elems/block) + block sums
__global__ __launch_bounds__(256) void scan_block_kernel(
    const int* __restrict__ in, int* __restrict__ out, int* __restrict__ part, int n) {
  __shared__ int tmp[256];
  int tid = threadIdx.x;
  int i = blockIdx.x * 256 + tid;
  int v = (i < n) ? in[i] : 0;
  tmp[tid] = v;
  __syncthreads();
  for (int d = 1; d < 256; d <<= 1) {
    int t = (tid >= d) ? tmp[tid - d] : 0;
    __syncthreads();
    tmp[tid] += t;
    __syncthreads();
  }
  if (i < n) out[i] = tmp[tid] - v;       // exclusive
  if (tid == 255) part[blockIdx.x] = tmp[255];
}

// K3b: scan the block sums (single block, nb <= 512)
__global__ __launch_bounds__(512) void scan_part_kernel(int* part, int nb) {
  __shared__ int tmp[512];
  int tid = threadIdx.x;
  int v = (tid < nb) ? part[tid] : 0;
  tmp[tid] = v;
  __syncthreads();
  for (int d = 1; d < 512; d <<= 1) {
    int t = (tid >= d) ? tmp[tid - d] : 0;
    __syncthreads();
    tmp[tid] += t;
    __syncthreads();
  }
  if (tid < nb) part[tid] = tmp[tid] - v; // exclusive
}

// K3c: add block offsets; write sentinel off[n] = E
__global__ __launch_bounds__(256) void scan_add_kernel(
    int* __restrict__ off, const int* __restrict__ part, int n, int total) {
  int i = blockIdx.x * 256 + threadIdx.x;
  if (i < n) off[i] += part[blockIdx.x];
  if (i == 0) off[n] = total;
}

// K4: atomic-free CSR fill using precomputed ranks
__global__ __launch_bounds__(256) void fill_kernel(
    const int* __restrict__ row, const int* __restrict__ col,
    const float* __restrict__ ew, const unsigned short* __restrict__ rank,
    const float* __restrict__ dis, const int* __restrict__ off,
    int2* __restrict__ csr, int E) {
  int e = blockIdx.x * 256 + threadIdx.x;
  if (e < E) {
    int c = col[e];
    int r = row[e];
    int slot = off[c] + (int)rank[e];
    csr[slot] = make_int2(r, __float_as_int(dis[r] * ew[e] * dis[c]));
  }
}

// GEMM: Y[n][128](fp16) = X[n][128](f32) @ W[128][128](f32); W staged in LDS.
// 4 threads per row, 32 output features per thread, fp16 RNE output.
__global__ __launch_bounds__(256) void gemm128_f16_kernel(
    const float* __restrict__ X, const float* __restrict__ W,
    uint* __restrict__ Y, int nrows) {
  __shared__ float Wl[HDIM * HDIM];
  int tid = threadIdx.x;
  for (int i = tid; i < HDIM * HDIM / 4; i += 256)
    ((float4*)Wl)[i] = ((const float4*)W)[i];
  __syncthreads();

  int rl = tid >> 2;
  int f0 = (tid & 3) * 32;
  int r = blockIdx.x * 64 + rl;
  if (r >= nrows) return;

  float acc[32];
#pragma unroll
  for (int j = 0; j < 32; ++j) acc[j] = 0.0f;

  const float* xr = X + (size_t)r * HDIM;
  for (int k = 0; k < HDIM; k += 4) {
    float4 xv = *(const float4*)(xr + k);
#pragma unroll
    for (int kk = 0; kk < 4; ++kk) {
      float xs = (kk == 0) ? xv.x : (kk == 1) ? xv.y : (kk == 2) ? xv.z : xv.w;
      const float* wr = &Wl[(k + kk) * HDIM + f0];
#pragma unroll
      for (int j = 0; j < 32; j += 4) {
        float4 wv = *(const float4*)(wr + j);
        acc[j]     += xs * wv.x;
        acc[j + 1] += xs * wv.y;
        acc[j + 2] += xs * wv.z;
        acc[j + 3] += xs * wv.w;
      }
    }
  }
  uint p[16];
#pragma unroll
  for (int j = 0; j < 32; j += 2) {
    __half2 hp = __floats2half2_rn(acc[j], acc[j + 1]);
    p[j >> 1] = *(uint*)&hp;
  }
  uint* yr = Y + ((size_t)r << 6) + (f0 >> 1);
#pragma unroll
  for (int q = 0; q < 4; ++q)
    ((uint4*)yr)[q] = make_uint4(p[4 * q], p[4 * q + 1], p[4 * q + 2], p[4 * q + 3]);
}

// Aggregate (pull): one wave per node; lanes hold 2 features (one fp16x2 word).
// out[c] = relu( dis[c]^2*xw[c] + sum_e nrm[e]*xw[src[e]] + bias ), f32 out.
__global__ __launch_bounds__(256) void agg_kernel(
    const uint* __restrict__ xw, const int2* __restrict__ csr,
    const float* __restrict__ dis, const int* __restrict__ off,
    const float* __restrict__ bias, float* __restrict__ out, int n) {
  int node = blockIdx.x * 4 + (threadIdx.x >> 6);
  if (node >= n) return;
  int lane = threadIdx.x & 63;
  float dc = dis[node];
  float ax, ay;
  {
    uint v = xw[((size_t)node << 6) + lane];
    float2 f = __half22float2(*(const __half2*)&v);
    float w = dc * dc;
    ax = w * f.x;
    ay = w * f.y;
  }
  int s = off[node], t = off[node + 1];
  for (int i = s; i < t; i += 4) {
    int lim = t - 1;
    int2 e0 = csr[i];
    int2 e1 = csr[min(i + 1, lim)];
    int2 e2 = csr[min(i + 2, lim)];
    int2 e3 = csr[min(i + 3, lim)];
    uint v0 = xw[((size_t)e0.x << 6) + lane];
    uint v1 = xw[((size_t)e1.x << 6) + lane];
    uint v2 = xw[((size_t)e2.x << 6) + lane];
    uint v3 = xw[((size_t)e3.x << 6) + lane];
    float n0 = __int_as_float(e0.y);
    float n1 = (i + 1 < t) ? __int_as_float(e1.y) : 0.0f;
    float n2 = (i + 2 < t) ? __int_as_float(e2.y) : 0.0f;
    float n3 = (i + 3 < t) ? __int_as_float(e3.y) : 0.0f;
    float2 f0 = __half22float2(*(const __half2*)&v0);
    float2 f1 = __half22float2(*(const __half2*)&v1);
    float2 f2 = __half22float2(*(const __half2*)&v2);
    float2 f3 = __half22float2(*(const __half2*)&v3);
    ax += n0 * f0.x; ay += n0 * f0.y;
    ax += n1 * f1.x; ay += n1 * f1.y;
    ax += n2 * f2.x; ay += n2 * f2.y;
    ax += n3 * f3.x; ay += n3 * f3.y;
  }
  float2 b = *(const float2*)(bias + lane * 2);
  ax = fmaxf(ax + b.x, 0.0f);
  ay = fmaxf(ay + b.y, 0.0f);
  *(float2*)(out + ((size_t)node << 7) + lane * 2) = make_float2(ax, ay);
}

// Mean-pool over sorted batch segments: one block per graph, no atomics.
__global__ __launch_bounds__(128) void pool_kernel(
    const float* __restrict__ h, const int* __restrict__ start,
    float* __restrict__ pooled) {
  int g = blockIdx.x;
  int f = threadIdx.x;
  int s = start[g], e = start[g + 1];
  float s0 = 0.0f, s1 = 0.0f;
  int r = s;
  for (; r + 2 <= e; r += 2) {
    s0 += h[(size_t)r * HDIM + f];
    s1 += h[(size_t)(r + 1) * HDIM + f];
  }
  if (r < e) s0 += h[(size_t)r * HDIM + f];
  float inv = 1.0f / (float)max(e - s, 1);
  pooled[g * HDIM + f] = (s0 + s1) * inv;
}

// Final: out[g][o] = dot(pooled[g], Wl[:,o]) + bl[o]
__global__ __launch_bounds__(64) void final_kernel(
    const float* __restrict__ pooled, const float* __restrict__ Wl,
    const float* __restrict__ bl, float* __restrict__ out) {
  int g = blockIdx.x;
  int lane = threadIdx.x;
  float p0 = pooled[g * HDIM + lane];
  float p1 = pooled[g * HDIM + 64 + lane];
#pragma unroll
  for (int o = 0; o < 2; ++o) {
    float s = p0 * Wl[lane * 2 + o] + p1 * Wl[(64 + lane) * 2 + o];
    for (int d = 32; d > 0; d >>= 1) s += __shfl_down(s, d);
    if (lane == 0) out[g * 2 + o] = s + bl[o];
  }
}

extern "C" void kernel_launch(void* const* d_in, const int* in_sizes, int n_in,
                              void* d_out, int out_size, void* d_ws, size_t ws_size,
                              hipStream_t stream) {
  const float* x     = (const float*)d_in[0];
  const int*   ei    = (const int*)d_in[1];
  const float* ew    = (const float*)d_in[2];
  const int*   batch = (const int*)d_in[3];
  const float* W1    = (const float*)d_in[4];
  const float* b1    = (const float*)d_in[5];
  const float* W2    = (const float*)d_in[6];
  const float* b2    = (const float*)d_in[7];
  const float* Wl    = (const float*)d_in[8];
  const float* bl    = (const float*)d_in[9];
  float* out = (float*)d_out;

  const int N = in_sizes[0] / HDIM;     // 100000
  const int E = in_sizes[2];            // 1600000
  const int G = out_size / 2;           // 512

  const int* row = ei;
  const int* col = ei + E;

  // ---- workspace layout (256B aligned) ----
  auto al = [](size_t v) { return (v + 255) & ~(size_t)255; };
  char* ws = (char*)d_ws;
  size_t o_dc64   = 0;                                   // u64[N] (zeroed)
  size_t zero_end = o_dc64   + al((size_t)N * 8);
  size_t o_rank   = zero_end;                            // u16[E]
  size_t o_cnt    = o_rank   + al((size_t)E * 2);        // i32[N]
  size_t o_dis    = o_cnt    + al((size_t)N * 4);        // f32[N]
  size_t o_start  = o_dis    + al((size_t)N * 4);        // i32[G+1]
  size_t o_off    = o_start  + al(((size_t)G + 1) * 4);  // i32[N+1]
  size_t o_part   = o_off    + al(((size_t)N + 1) * 4);  // i32[512]
  size_t o_csr    = o_part   + al(2048);                 // int2[E]
  size_t o_xw     = o_csr    + al((size_t)E * 8);        // fp16x2 uint[N*64]
  size_t o_h      = o_xw     + al((size_t)N * 64 * 4);   // f32[N*128]
  size_t o_pooled = o_h      + al((size_t)N * HDIM * 4); // f32[G*128]

  u64*   dc64    = (u64*)  (ws + o_dc64);
  unsigned short* rank = (unsigned short*)(ws + o_rank);
  int*   cnt     = (int*)  (ws + o_cnt);
  float* dis     = (float*)(ws + o_dis);
  int*   start   = (int*)  (ws + o_start);
  int*   off     = (int*)  (ws + o_off);
  int*   part    = (int*)  (ws + o_part);
  int2*  csr     = (int2*) (ws + o_csr);
  uint*  xw      = (uint*) (ws + o_xw);
  float* hbuf    = (float*)(ws + o_h);
  float* pooled  = (float*)(ws + o_pooled);

  // zero the packed deg/cnt accumulator
  hipMemsetAsync(ws, 0, zero_end, stream);

  int EB = (E + 255) / 256;
  int NB = (N + 255) / 256;

  hist_kernel<<<EB, 256, 0, stream>>>(col, ew, dc64, rank, E);
  node_kernel<<<NB, 256, 0, stream>>>(dc64, dis, cnt, batch, start, N, G);

  scan_block_kernel<<<NB, 256, 0, stream>>>(cnt, off, part, N);
  scan_part_kernel<<<1, 512, 0, stream>>>(part, NB);
  scan_add_kernel<<<NB, 256, 0, stream>>>(off, part, N, E);

  fill_kernel<<<EB, 256, 0, stream>>>(row, col, ew, rank, dis, off, csr, E);

  int GB = (N + 63) / 64;     // gemm blocks
  int AB = (N + 3) / 4;       // agg blocks (4 waves/block)

  // layer 1: xw = fp16(x @ W1) ; h1 = relu(agg(xw) + b1)   (f32)
  gemm128_f16_kernel<<<GB, 256, 0, stream>>>(x, W1, xw, N);
  agg_kernel<<<AB, 256, 0, stream>>>(xw, csr, dis, off, b1, hbuf, N);

  // layer 2: xw2 = fp16(h1 @ W2) ; h2 = relu(agg(xw2) + b2) (f32)
  gemm128_f16_kernel<<<GB, 256, 0, stream>>>(hbuf, W2, xw, N);
  agg_kernel<<<AB, 256, 0, stream>>>(xw, csr, dis, off, b2, hbuf, N);

  // mean-pool per sorted-batch segment, then linear head
  pool_kernel<<<G, 128, 0, stream>>>(hbuf, start, pooled);
  final_kernel<<<G, 64, 0, stream>>>(pooled, Wl, bl, out);
}

// Round 4
// 425.959 us; speedup vs baseline: 2.2799x; 1.2416x over previous
//
#include <hip/hip_runtime.h>
#include <hip/hip_fp16.h>

// ---------------------------------------------------------------------------
// GCN graph classifier: 2x GCNConv(128->128) + global_mean_pool + Linear(128->2)
// R4: MFMA GEMM (16x16x32 f16, swapped operands: D = W^T * X^T so B-frags are
// contiguous row-slices of X and stores are 8B packed fp16). W^T staged in LDS
// fp16 with XOR swizzle (bank-conflict-free). agg outputs packed fp16.
// Packed 64-bit atomic histogram -> rank -> atomic-free CSR fill (R3).
// ---------------------------------------------------------------------------

#define HDIM 128
typedef unsigned int uint;
typedef unsigned long long u64;
typedef _Float16 half8 __attribute__((ext_vector_type(8)));
typedef _Float16 half2v __attribute__((ext_vector_type(2)));
typedef float f32x4 __attribute__((ext_vector_type(4)));

// K1: one packed atomic per edge; returns rank within destination node.
__global__ __launch_bounds__(256) void hist_kernel(
    const int* __restrict__ col, const float* __restrict__ ew,
    u64* __restrict__ dc64, unsigned short* __restrict__ rank, int E) {
  int e = blockIdx.x * 256 + threadIdx.x;
  if (e < E) {
    int c = col[e];
    u64 pack = ((u64)1 << 40) + (u64)__float2uint_rn(ew[e] * 1048576.0f);
    u64 old = atomicAdd(&dc64[c], pack);
    rank[e] = (unsigned short)(old >> 40);
  }
}

// K2: unpack deg -> dis = rsqrt(deg+1), cnt; graph segment starts (sorted batch)
__global__ __launch_bounds__(256) void node_kernel(
    const u64* __restrict__ dc64, float* __restrict__ dis, int* __restrict__ cnt,
    const int* __restrict__ batch, int* __restrict__ start, int n, int G) {
  int i = blockIdx.x * 256 + threadIdx.x;
  if (i >= n) return;
  u64 v = dc64[i];
  float deg = (float)(v & 0xFFFFFFFFFFull) * (1.0f / 1048576.0f);
  dis[i] = rsqrtf(deg + 1.0f);
  cnt[i] = (int)(v >> 40);
  int b = batch[i];
  if (i == 0) {
    for (int h = 0; h <= b; ++h) start[h] = 0;
  } else {
    int bp = batch[i - 1];
    for (int h = bp + 1; h <= b; ++h) start[h] = i;
  }
  if (i == n - 1) {
    for (int h = b + 1; h <= G; ++h) start[h] = n;
  }
}

// K3a: per-block exclusive scan (256 elems/block) + block sums
__global__ __launch_bounds__(256) void scan_block_kernel(
    const int* __restrict__ in, int* __restrict__ out, int* __restrict__ part, int n) {
  __shared__ int tmp[256];
  int tid = threadIdx.x;
  int i = blockIdx.x * 256 + tid;
  int v = (i < n) ? in[i] : 0;
  tmp[tid] = v;
  __syncthreads();
  for (int d = 1; d < 256; d <<= 1) {
    int t = (tid >= d) ? tmp[tid - d] : 0;
    __syncthreads();
    tmp[tid] += t;
    __syncthreads();
  }
  if (i < n) out[i] = tmp[tid] - v;       // exclusive
  if (tid == 255) part[blockIdx.x] = tmp[255];
}

// K3b: scan the block sums (single block, nb <= 512)
__global__ __launch_bounds__(512) void scan_part_kernel(int* part, int nb) {
  __shared__ int tmp[512];
  int tid = threadIdx.x;
  int v = (tid < nb) ? part[tid] : 0;
  tmp[tid] = v;
  __syncthreads();
  for (int d = 1; d < 512; d <<= 1) {
    int t = (tid >= d) ? tmp[tid - d] : 0;
    __syncthreads();
    tmp[tid] += t;
    __syncthreads();
  }
  if (tid < nb) part[tid] = tmp[tid] - v; // exclusive
}

// K3c: add block offsets; write sentinel off[n] = E
__global__ __launch_bounds__(256) void scan_add_kernel(
    int* __restrict__ off, const int* __restrict__ part, int n, int total) {
  int i = blockIdx.x * 256 + threadIdx.x;
  if (i < n) off[i] += part[blockIdx.x];
  if (i == 0) off[n] = total;
}

// K4: atomic-free CSR fill using precomputed ranks
__global__ __launch_bounds__(256) void fill_kernel(
    const int* __restrict__ row, const int* __restrict__ col,
    const float* __restrict__ ew, const unsigned short* __restrict__ rank,
    const float* __restrict__ dis, const int* __restrict__ off,
    int2* __restrict__ csr, int E) {
  int e = blockIdx.x * 256 + threadIdx.x;
  if (e < E) {
    int c = col[e];
    int r = row[e];
    int slot = off[c] + (int)rank[e];
    csr[slot] = make_int2(r, __float_as_int(dis[r] * ew[e] * dis[c]));
  }
}

// MFMA GEMM: Y[n][128](fp16 pairs) = A[n][128] @ W[128][128](f32 in global).
// Swapped operands: D = Wt * X^T per 16-row strip.
//   a-frag (LDS, swizzled): lane l -> Wt[16cf+(l&15)][32kk+8*(l>>4)+i]
//   b-frag (global):        lane l -> A[row0+(l&15)][32kk+8*(l>>4)+i]
//   D: lane l, reg j -> out[row0+(l&15)][16cf+4*(l>>4)+j]
template <typename AT>
__global__ __launch_bounds__(256, 4) void gemm_mfma_kernel(
    const AT* __restrict__ A, const float* __restrict__ W,
    uint* __restrict__ Y, int n, int nstrip) {
  __shared__ __align__(16) char Wt[32768];   // fp16 [128 c][128 k], swizzled
  int tid = threadIdx.x;
  {
    const float4* Wf4 = (const float4*)W;
    for (int i = tid; i < 2048; i += 256) {
      int k = (i >> 5) * 2;            // even k; pack (k, k+1)
      int c4 = (i & 31) * 4;
      float4 wa = Wf4[(k << 5) + (i & 31)];
      float4 wb = Wf4[((k + 1) << 5) + (i & 31)];
      float a0[4] = {wa.x, wa.y, wa.z, wa.w};
      float b0[4] = {wb.x, wb.y, wb.z, wb.w};
#pragma unroll
      for (int j = 0; j < 4; ++j) {
        int c = c4 + j;
        int byte = c * 256 + k * 2;
        byte ^= ((c & 7) << 4);
        half2v hv;
        hv[0] = (_Float16)a0[j];
        hv[1] = (_Float16)b0[j];
        *(half2v*)&Wt[byte] = hv;
      }
    }
  }
  __syncthreads();

  int wave = tid >> 6, lane = tid & 63;
  int l15 = lane & 15, l4 = lane >> 4;
  int stride = gridDim.x * 4;
  for (int s = blockIdx.x * 4 + wave; s < nstrip; s += stride) {
    int row0 = s << 4;
    int xr = row0 + l15;
    int xrl = min(xr, n - 1);
    // b-frags: 4 x 16B from this lane's X row
    half8 bf[4];
    if constexpr (sizeof(AT) == 4) {
      const float* ap = (const float*)A + (size_t)xrl * HDIM + l4 * 8;
#pragma unroll
      for (int kk = 0; kk < 4; ++kk) {
        float4 u = *(const float4*)(ap + kk * 32);
        float4 v = *(const float4*)(ap + kk * 32 + 4);
        half8 h;
        h[0] = (_Float16)u.x; h[1] = (_Float16)u.y;
        h[2] = (_Float16)u.z; h[3] = (_Float16)u.w;
        h[4] = (_Float16)v.x; h[5] = (_Float16)v.y;
        h[6] = (_Float16)v.z; h[7] = (_Float16)v.w;
        bf[kk] = h;
      }
    } else {
      const half8* ap = (const half8*)((const _Float16*)A + (size_t)xrl * HDIM + l4 * 8);
#pragma unroll
      for (int kk = 0; kk < 4; ++kk) bf[kk] = ap[kk * 4];
    }
    f32x4 acc[8];
#pragma unroll
    for (int cf = 0; cf < 8; ++cf) acc[cf] = (f32x4){0.f, 0.f, 0.f, 0.f};
#pragma unroll
    for (int kk = 0; kk < 4; ++kk) {
#pragma unroll
      for (int cf = 0; cf < 8; ++cf) {
        int c = cf * 16 + l15;
        int byte = c * 256 + kk * 64 + l4 * 16;
        byte ^= ((c & 7) << 4);
        half8 af = *(half8*)&Wt[byte];
        acc[cf] = __builtin_amdgcn_mfma_f32_16x16x32_f16(af, bf[kk], acc[cf], 0, 0, 0);
      }
    }
    if (xr < n) {
      uint* yr = Y + ((size_t)xr << 6) + l4 * 2;
#pragma unroll
      for (int cf = 0; cf < 8; ++cf) {
        __half2 p0 = __floats2half2_rn(acc[cf][0], acc[cf][1]);
        __half2 p1 = __floats2half2_rn(acc[cf][2], acc[cf][3]);
        *(uint2*)(yr + cf * 8) = make_uint2(*(uint*)&p0, *(uint*)&p1);
      }
    }
  }
}

// Aggregate (pull): one wave per node; lanes hold 2 features (one fp16x2 word).
// out[c] = relu( dis[c]^2*xw[c] + sum_e nrm[e]*xw[src[e]] + bias ), fp16 out.
__global__ __launch_bounds__(256) void agg_kernel(
    const uint* __restrict__ xw, const int2* __restrict__ csr,
    const float* __restrict__ dis, const int* __restrict__ off,
    const float* __restrict__ bias, uint* __restrict__ out, int n) {
  int node = blockIdx.x * 4 + (threadIdx.x >> 6);
  if (node >= n) return;
  int lane = threadIdx.x & 63;
  float dc = dis[node];
  float ax, ay;
  {
    uint v = xw[((size_t)node << 6) + lane];
    float2 f = __half22float2(*(const __half2*)&v);
    float w = dc * dc;
    ax = w * f.x;
    ay = w * f.y;
  }
  int s = off[node], t = off[node + 1];
  for (int i = s; i < t; i += 4) {
    int lim = t - 1;
    int2 e0 = csr[i];
    int2 e1 = csr[min(i + 1, lim)];
    int2 e2 = csr[min(i + 2, lim)];
    int2 e3 = csr[min(i + 3, lim)];
    uint v0 = xw[((size_t)e0.x << 6) + lane];
    uint v1 = xw[((size_t)e1.x << 6) + lane];
    uint v2 = xw[((size_t)e2.x << 6) + lane];
    uint v3 = xw[((size_t)e3.x << 6) + lane];
    float n0 = __int_as_float(e0.y);
    float n1 = (i + 1 < t) ? __int_as_float(e1.y) : 0.0f;
    float n2 = (i + 2 < t) ? __int_as_float(e2.y) : 0.0f;
    float n3 = (i + 3 < t) ? __int_as_float(e3.y) : 0.0f;
    float2 f0 = __half22float2(*(const __half2*)&v0);
    float2 f1 = __half22float2(*(const __half2*)&v1);
    float2 f2 = __half22float2(*(const __half2*)&v2);
    float2 f3 = __half22float2(*(const __half2*)&v3);
    ax += n0 * f0.x; ay += n0 * f0.y;
    ax += n1 * f1.x; ay += n1 * f1.y;
    ax += n2 * f2.x; ay += n2 * f2.y;
    ax += n3 * f3.x; ay += n3 * f3.y;
  }
  float2 b = *(const float2*)(bias + lane * 2);
  ax = fmaxf(ax + b.x, 0.0f);
  ay = fmaxf(ay + b.y, 0.0f);
  __half2 p = __floats2half2_rn(ax, ay);
  out[((size_t)node << 6) + lane] = *(uint*)&p;
}

// Mean-pool over sorted batch segments (fp16 input): one block per graph.
__global__ __launch_bounds__(64) void pool_kernel(
    const uint* __restrict__ h, const int* __restrict__ start,
    float* __restrict__ pooled) {
  int g = blockIdx.x;
  int f = threadIdx.x;          // 64 threads, 2 features each
  int s = start[g], e = start[g + 1];
  float s0 = 0.0f, s1 = 0.0f;
  for (int r = s; r < e; ++r) {
    uint v = h[((size_t)r << 6) + f];
    float2 fv = __half22float2(*(const __half2*)&v);
    s0 += fv.x;
    s1 += fv.y;
  }
  float inv = 1.0f / (float)max(e - s, 1);
  pooled[g * HDIM + 2 * f]     = s0 * inv;
  pooled[g * HDIM + 2 * f + 1] = s1 * inv;
}

// Final: out[g][o] = dot(pooled[g], Wl[:,o]) + bl[o]
__global__ __launch_bounds__(64) void final_kernel(
    const float* __restrict__ pooled, const float* __restrict__ Wl,
    const float* __restrict__ bl, float* __restrict__ out) {
  int g = blockIdx.x;
  int lane = threadIdx.x;
  float p0 = pooled[g * HDIM + lane];
  float p1 = pooled[g * HDIM + 64 + lane];
#pragma unroll
  for (int o = 0; o < 2; ++o) {
    float s = p0 * Wl[lane * 2 + o] + p1 * Wl[(64 + lane) * 2 + o];
    for (int d = 32; d > 0; d >>= 1) s += __shfl_down(s, d);
    if (lane == 0) out[g * 2 + o] = s + bl[o];
  }
}

extern "C" void kernel_launch(void* const* d_in, const int* in_sizes, int n_in,
                              void* d_out, int out_size, void* d_ws, size_t ws_size,
                              hipStream_t stream) {
  const float* x     = (const float*)d_in[0];
  const int*   ei    = (const int*)d_in[1];
  const float* ew    = (const float*)d_in[2];
  const int*   batch = (const int*)d_in[3];
  const float* W1    = (const float*)d_in[4];
  const float* b1    = (const float*)d_in[5];
  const float* W2    = (const float*)d_in[6];
  const float* b2    = (const float*)d_in[7];
  const float* Wl    = (const float*)d_in[8];
  const float* bl    = (const float*)d_in[9];
  float* out = (float*)d_out;

  const int N = in_sizes[0] / HDIM;     // 100000
  const int E = in_sizes[2];            // 1600000
  const int G = out_size / 2;           // 512

  const int* row = ei;
  const int* col = ei + E;

  // ---- workspace layout (256B aligned) ----
  auto al = [](size_t v) { return (v + 255) & ~(size_t)255; };
  char* ws = (char*)d_ws;
  size_t o_dc64   = 0;                                   // u64[N] (zeroed)
  size_t zero_end = o_dc64   + al((size_t)N * 8);
  size_t o_rank   = zero_end;                            // u16[E]
  size_t o_cnt    = o_rank   + al((size_t)E * 2);        // i32[N]
  size_t o_dis    = o_cnt    + al((size_t)N * 4);        // f32[N]
  size_t o_start  = o_dis    + al((size_t)N * 4);        // i32[G+1]
  size_t o_off    = o_start  + al(((size_t)G + 1) * 4);  // i32[N+1]
  size_t o_part   = o_off    + al(((size_t)N + 1) * 4);  // i32[512]
  size_t o_csr    = o_part   + al(2048);                 // int2[E]
  size_t o_xw     = o_csr    + al((size_t)E * 8);        // fp16x2 uint[N*64]
  size_t o_h      = o_xw     + al((size_t)N * 64 * 4);   // fp16x2 uint[N*64]
  size_t o_pooled = o_h      + al((size_t)N * 64 * 4);   // f32[G*128]

  u64*   dc64    = (u64*)  (ws + o_dc64);
  unsigned short* rank = (unsigned short*)(ws + o_rank);
  int*   cnt     = (int*)  (ws + o_cnt);
  float* dis     = (float*)(ws + o_dis);
  int*   start   = (int*)  (ws + o_start);
  int*   off     = (int*)  (ws + o_off);
  int*   part    = (int*)  (ws + o_part);
  int2*  csr     = (int2*) (ws + o_csr);
  uint*  xw      = (uint*) (ws + o_xw);
  uint*  hbuf    = (uint*) (ws + o_h);
  float* pooled  = (float*)(ws + o_pooled);

  hipMemsetAsync(ws, 0, zero_end, stream);

  int EB = (E + 255) / 256;
  int NB = (N + 255) / 256;

  hist_kernel<<<EB, 256, 0, stream>>>(col, ew, dc64, rank, E);
  node_kernel<<<NB, 256, 0, stream>>>(dc64, dis, cnt, batch, start, N, G);

  scan_block_kernel<<<NB, 256, 0, stream>>>(cnt, off, part, N);
  scan_part_kernel<<<1, 512, 0, stream>>>(part, NB);
  scan_add_kernel<<<NB, 256, 0, stream>>>(off, part, N, E);

  fill_kernel<<<EB, 256, 0, stream>>>(row, col, ew, rank, dis, off, csr, E);

  int nstrip = (N + 15) / 16;
  int MB = 1024;              // mfma gemm blocks (grid-stride over strips)
  int AB = (N + 3) / 4;       // agg blocks (4 waves/block)

  // layer 1: xw = fp16(x @ W1) ; h1 = fp16(relu(agg(xw) + b1))
  gemm_mfma_kernel<float><<<MB, 256, 0, stream>>>(x, W1, xw, N, nstrip);
  agg_kernel<<<AB, 256, 0, stream>>>(xw, csr, dis, off, b1, hbuf, N);

  // layer 2: xw2 = fp16(h1 @ W2) ; h2 = fp16(relu(agg(xw2) + b2))
  gemm_mfma_kernel<_Float16><<<MB, 256, 0, stream>>>(
      (const _Float16*)hbuf, W2, xw, N, nstrip);
  agg_kernel<<<AB, 256, 0, stream>>>(xw, csr, dis, off, b2, hbuf, N);

  // mean-pool per sorted-batch segment, then linear head
  pool_kernel<<<G, 64, 0, stream>>>(hbuf, start, pooled);
  final_kernel<<<G, 64, 0, stream>>>(pooled, Wl, bl, out);
}

// Round 5
// 370.758 us; speedup vs baseline: 2.6193x; 1.1489x over previous
//
#include <hip/hip_runtime.h>
#include <hip/hip_fp16.h>

// ---------------------------------------------------------------------------
// GCN graph classifier: 2x GCNConv(128->128) + global_mean_pool + Linear(128->2)
// R5: hist (atomic-bound) fused with gemm1 (MFMA-bound) via block-range split
// to overlap independent DAG branches. agg with clean 8/4-wide unroll + scalar
// tail, dis[col] factored out of csr norm (saves a random gather in fill).
// ---------------------------------------------------------------------------

#define HDIM 128
typedef unsigned int uint;
typedef unsigned long long u64;
typedef _Float16 half8 __attribute__((ext_vector_type(8)));
typedef _Float16 half2v __attribute__((ext_vector_type(2)));
typedef float f32x4 __attribute__((ext_vector_type(4)));

// ---- shared gemm body: Y[n][128](fp16 pairs) = A[n][128] @ W[128][128] ----
// Swapped operands: D = Wt * X^T per 16-row strip (layout validated R4).
template <typename AT>
__device__ __forceinline__ void gemm_body(
    const AT* __restrict__ A, const float* __restrict__ W, uint* __restrict__ Y,
    int n, int nstrip, int tid, int bid, int nblk, char* Wt) {
  {
    const float4* Wf4 = (const float4*)W;
    for (int i = tid; i < 2048; i += 256) {
      int k = (i >> 5) * 2;            // even k; pack (k, k+1)
      int c4 = (i & 31) * 4;
      float4 wa = Wf4[(k << 5) + (i & 31)];
      float4 wb = Wf4[((k + 1) << 5) + (i & 31)];
      float a0[4] = {wa.x, wa.y, wa.z, wa.w};
      float b0[4] = {wb.x, wb.y, wb.z, wb.w};
#pragma unroll
      for (int j = 0; j < 4; ++j) {
        int c = c4 + j;
        int byte = c * 256 + k * 2;
        byte ^= ((c & 7) << 4);
        half2v hv;
        hv[0] = (_Float16)a0[j];
        hv[1] = (_Float16)b0[j];
        *(half2v*)&Wt[byte] = hv;
      }
    }
  }
  __syncthreads();

  int wave = tid >> 6, lane = tid & 63;
  int l15 = lane & 15, l4 = lane >> 4;
  int stride = nblk * 4;
  for (int s = bid * 4 + wave; s < nstrip; s += stride) {
    int row0 = s << 4;
    int xr = row0 + l15;
    int xrl = min(xr, n - 1);
    half8 bf[4];
    if constexpr (sizeof(AT) == 4) {
      const float* ap = (const float*)A + (size_t)xrl * HDIM + l4 * 8;
#pragma unroll
      for (int kk = 0; kk < 4; ++kk) {
        float4 u = *(const float4*)(ap + kk * 32);
        float4 v = *(const float4*)(ap + kk * 32 + 4);
        half8 h;
        h[0] = (_Float16)u.x; h[1] = (_Float16)u.y;
        h[2] = (_Float16)u.z; h[3] = (_Float16)u.w;
        h[4] = (_Float16)v.x; h[5] = (_Float16)v.y;
        h[6] = (_Float16)v.z; h[7] = (_Float16)v.w;
        bf[kk] = h;
      }
    } else {
      const half8* ap = (const half8*)((const _Float16*)A + (size_t)xrl * HDIM + l4 * 8);
#pragma unroll
      for (int kk = 0; kk < 4; ++kk) bf[kk] = ap[kk * 4];
    }
    f32x4 acc[8];
#pragma unroll
    for (int cf = 0; cf < 8; ++cf) acc[cf] = (f32x4){0.f, 0.f, 0.f, 0.f};
#pragma unroll
    for (int kk = 0; kk < 4; ++kk) {
#pragma unroll
      for (int cf = 0; cf < 8; ++cf) {
        int c = cf * 16 + l15;
        int byte = c * 256 + kk * 64 + l4 * 16;
        byte ^= ((c & 7) << 4);
        half8 af = *(half8*)&Wt[byte];
        acc[cf] = __builtin_amdgcn_mfma_f32_16x16x32_f16(af, bf[kk], acc[cf], 0, 0, 0);
      }
    }
    if (xr < n) {
      uint* yr = Y + ((size_t)xr << 6) + l4 * 2;
#pragma unroll
      for (int cf = 0; cf < 8; ++cf) {
        __half2 p0 = __floats2half2_rn(acc[cf][0], acc[cf][1]);
        __half2 p1 = __floats2half2_rn(acc[cf][2], acc[cf][3]);
        *(uint2*)(yr + cf * 8) = make_uint2(*(uint*)&p0, *(uint*)&p1);
      }
    }
  }
}

// K1: fused. Blocks [0,HB): packed 64-bit atomic histogram + rank.
// Blocks [HB,HB+nblk): gemm1 (independent of edges) — hides under hist.
__global__ __launch_bounds__(256) void hist_gemm1_kernel(
    const int* __restrict__ col, const float* __restrict__ ew,
    u64* __restrict__ dc64, unsigned short* __restrict__ rank, int E, int HB,
    const float* __restrict__ A, const float* __restrict__ W,
    uint* __restrict__ Y, int n, int nstrip, int nblk) {
  __shared__ __align__(16) char Wt[32768];
  int bid = blockIdx.x;
  if (bid < HB) {
    int e = bid * 256 + threadIdx.x;
    if (e < E) {
      int c = col[e];
      u64 pack = ((u64)1 << 40) + (u64)__float2uint_rn(ew[e] * 1048576.0f);
      u64 old = atomicAdd(&dc64[c], pack);
      rank[e] = (unsigned short)(old >> 40);
    }
    return;
  }
  gemm_body<float>(A, W, Y, n, nstrip, threadIdx.x, bid - HB, nblk, Wt);
}

// standalone gemm for layer 2 (fp16 A)
__global__ __launch_bounds__(256, 4) void gemm_mfma_kernel(
    const _Float16* __restrict__ A, const float* __restrict__ W,
    uint* __restrict__ Y, int n, int nstrip) {
  __shared__ __align__(16) char Wt[32768];
  gemm_body<_Float16>(A, W, Y, n, nstrip, threadIdx.x, blockIdx.x, gridDim.x, Wt);
}

// K2: fused node unpack (dis, graph starts) + per-block scan of counts
__global__ __launch_bounds__(256) void node_scan_kernel(
    const u64* __restrict__ dc64, float* __restrict__ dis,
    const int* __restrict__ batch, int* __restrict__ start,
    int* __restrict__ off, int* __restrict__ part, int n, int G) {
  __shared__ int tmp[256];
  int tid = threadIdx.x;
  int i = blockIdx.x * 256 + tid;
  int v = 0;
  if (i < n) {
    u64 p = dc64[i];
    v = (int)(p >> 40);
    float deg = (float)(p & 0xFFFFFFFFFFull) * (1.0f / 1048576.0f);
    dis[i] = rsqrtf(deg + 1.0f);
    int b = batch[i];
    if (i == 0) {
      for (int h = 0; h <= b; ++h) start[h] = 0;
    } else {
      int bp = batch[i - 1];
      for (int h = bp + 1; h <= b; ++h) start[h] = i;
    }
    if (i == n - 1) {
      for (int h = b + 1; h <= G; ++h) start[h] = n;
    }
  }
  tmp[tid] = v;
  __syncthreads();
  for (int d = 1; d < 256; d <<= 1) {
    int t = (tid >= d) ? tmp[tid - d] : 0;
    __syncthreads();
    tmp[tid] += t;
    __syncthreads();
  }
  if (i < n) off[i] = tmp[tid] - v;       // exclusive
  if (tid == 255) part[blockIdx.x] = tmp[255];
}

// K3b: scan the block sums (single block, nb <= 512)
__global__ __launch_bounds__(512) void scan_part_kernel(int* part, int nb) {
  __shared__ int tmp[512];
  int tid = threadIdx.x;
  int v = (tid < nb) ? part[tid] : 0;
  tmp[tid] = v;
  __syncthreads();
  for (int d = 1; d < 512; d <<= 1) {
    int t = (tid >= d) ? tmp[tid - d] : 0;
    __syncthreads();
    tmp[tid] += t;
    __syncthreads();
  }
  if (tid < nb) part[tid] = tmp[tid] - v; // exclusive
}

// K3c: add block offsets; write sentinel off[n] = E
__global__ __launch_bounds__(256) void scan_add_kernel(
    int* __restrict__ off, const int* __restrict__ part, int n, int total) {
  int i = blockIdx.x * 256 + threadIdx.x;
  if (i < n) off[i] += part[blockIdx.x];
  if (i == 0) off[n] = total;
}

// K4: atomic-free CSR fill; norm = dis[row]*ew only (dis[col] in agg epilogue)
__global__ __launch_bounds__(256) void fill_kernel(
    const int* __restrict__ row, const int* __restrict__ col,
    const float* __restrict__ ew, const unsigned short* __restrict__ rank,
    const float* __restrict__ dis, const int* __restrict__ off,
    int2* __restrict__ csr, int E) {
  int e = blockIdx.x * 256 + threadIdx.x;
  if (e < E) {
    int c = col[e];
    int r = row[e];
    int slot = off[c] + (int)rank[e];
    csr[slot] = make_int2(r, __float_as_int(dis[r] * ew[e]));
  }
}

// Aggregate (pull): one wave per node; lanes hold 2 features (one fp16x2 word).
// out = relu( dc*( sum_e nrm_e*xw[src_e] + dc*xw_self ) + bias ), fp16 out.
__global__ __launch_bounds__(256) void agg_kernel(
    const uint* __restrict__ xw, const int2* __restrict__ csr,
    const float* __restrict__ dis, const int* __restrict__ off,
    const float* __restrict__ bias, uint* __restrict__ out, int n) {
  int node = blockIdx.x * 4 + (threadIdx.x >> 6);
  if (node >= n) return;
  int lane = threadIdx.x & 63;
  const uint* xwl = xw + lane;
  float dc = dis[node];
  float ax, ay;
  {
    uint v = xwl[(size_t)node << 6];
    float2 f = __half22float2(*(const __half2*)&v);
    ax = dc * f.x;                 // seed with dc*xw_self -> dc^2 after epilogue
    ay = dc * f.y;
  }
  int s = off[node], t = off[node + 1];
  int i = s;
  for (; i + 8 <= t; i += 8) {
    int2 e0 = csr[i],     e1 = csr[i + 1], e2 = csr[i + 2], e3 = csr[i + 3];
    int2 e4 = csr[i + 4], e5 = csr[i + 5], e6 = csr[i + 6], e7 = csr[i + 7];
    uint v0 = xwl[(size_t)e0.x << 6];
    uint v1 = xwl[(size_t)e1.x << 6];
    uint v2 = xwl[(size_t)e2.x << 6];
    uint v3 = xwl[(size_t)e3.x << 6];
    uint v4 = xwl[(size_t)e4.x << 6];
    uint v5 = xwl[(size_t)e5.x << 6];
    uint v6 = xwl[(size_t)e6.x << 6];
    uint v7 = xwl[(size_t)e7.x << 6];
    float2 f0 = __half22float2(*(const __half2*)&v0);
    float2 f1 = __half22float2(*(const __half2*)&v1);
    float2 f2 = __half22float2(*(const __half2*)&v2);
    float2 f3 = __half22float2(*(const __half2*)&v3);
    float2 f4 = __half22float2(*(const __half2*)&v4);
    float2 f5 = __half22float2(*(const __half2*)&v5);
    float2 f6 = __half22float2(*(const __half2*)&v6);
    float2 f7 = __half22float2(*(const __half2*)&v7);
    ax += __int_as_float(e0.y) * f0.x; ay += __int_as_float(e0.y) * f0.y;
    ax += __int_as_float(e1.y) * f1.x; ay += __int_as_float(e1.y) * f1.y;
    ax += __int_as_float(e2.y) * f2.x; ay += __int_as_float(e2.y) * f2.y;
    ax += __int_as_float(e3.y) * f3.x; ay += __int_as_float(e3.y) * f3.y;
    ax += __int_as_float(e4.y) * f4.x; ay += __int_as_float(e4.y) * f4.y;
    ax += __int_as_float(e5.y) * f5.x; ay += __int_as_float(e5.y) * f5.y;
    ax += __int_as_float(e6.y) * f6.x; ay += __int_as_float(e6.y) * f6.y;
    ax += __int_as_float(e7.y) * f7.x; ay += __int_as_float(e7.y) * f7.y;
  }
  for (; i + 4 <= t; i += 4) {
    int2 e0 = csr[i], e1 = csr[i + 1], e2 = csr[i + 2], e3 = csr[i + 3];
    uint v0 = xwl[(size_t)e0.x << 6];
    uint v1 = xwl[(size_t)e1.x << 6];
    uint v2 = xwl[(size_t)e2.x << 6];
    uint v3 = xwl[(size_t)e3.x << 6];
    float2 f0 = __half22float2(*(const __half2*)&v0);
    float2 f1 = __half22float2(*(const __half2*)&v1);
    float2 f2 = __half22float2(*(const __half2*)&v2);
    float2 f3 = __half22float2(*(const __half2*)&v3);
    ax += __int_as_float(e0.y) * f0.x; ay += __int_as_float(e0.y) * f0.y;
    ax += __int_as_float(e1.y) * f1.x; ay += __int_as_float(e1.y) * f1.y;
    ax += __int_as_float(e2.y) * f2.x; ay += __int_as_float(e2.y) * f2.y;
    ax += __int_as_float(e3.y) * f3.x; ay += __int_as_float(e3.y) * f3.y;
  }
  for (; i < t; ++i) {
    int2 e = csr[i];
    uint v = xwl[(size_t)e.x << 6];
    float2 f = __half22float2(*(const __half2*)&v);
    float nn = __int_as_float(e.y);
    ax += nn * f.x;
    ay += nn * f.y;
  }
  float2 b = *(const float2*)(bias + lane * 2);
  ax = fmaxf(dc * ax + b.x, 0.0f);
  ay = fmaxf(dc * ay + b.y, 0.0f);
  __half2 p = __floats2half2_rn(ax, ay);
  out[((size_t)node << 6) + lane] = *(uint*)&p;
}

// Mean-pool over sorted batch segments (fp16 input): one block per graph.
__global__ __launch_bounds__(64) void pool_kernel(
    const uint* __restrict__ h, const int* __restrict__ start,
    float* __restrict__ pooled) {
  int g = blockIdx.x;
  int f = threadIdx.x;          // 64 threads, 2 features each
  int s = start[g], e = start[g + 1];
  float s0 = 0.0f, s1 = 0.0f;
  for (int r = s; r < e; ++r) {
    uint v = h[((size_t)r << 6) + f];
    float2 fv = __half22float2(*(const __half2*)&v);
    s0 += fv.x;
    s1 += fv.y;
  }
  float inv = 1.0f / (float)max(e - s, 1);
  pooled[g * HDIM + 2 * f]     = s0 * inv;
  pooled[g * HDIM + 2 * f + 1] = s1 * inv;
}

// Final: out[g][o] = dot(pooled[g], Wl[:,o]) + bl[o]
__global__ __launch_bounds__(64) void final_kernel(
    const float* __restrict__ pooled, const float* __restrict__ Wl,
    const float* __restrict__ bl, float* __restrict__ out) {
  int g = blockIdx.x;
  int lane = threadIdx.x;
  float p0 = pooled[g * HDIM + lane];
  float p1 = pooled[g * HDIM + 64 + lane];
#pragma unroll
  for (int o = 0; o < 2; ++o) {
    float s = p0 * Wl[lane * 2 + o] + p1 * Wl[(64 + lane) * 2 + o];
    for (int d = 32; d > 0; d >>= 1) s += __shfl_down(s, d);
    if (lane == 0) out[g * 2 + o] = s + bl[o];
  }
}

extern "C" void kernel_launch(void* const* d_in, const int* in_sizes, int n_in,
                              void* d_out, int out_size, void* d_ws, size_t ws_size,
                              hipStream_t stream) {
  const float* x     = (const float*)d_in[0];
  const int*   ei    = (const int*)d_in[1];
  const float* ew    = (const float*)d_in[2];
  const int*   batch = (const int*)d_in[3];
  const float* W1    = (const float*)d_in[4];
  const float* b1    = (const float*)d_in[5];
  const float* W2    = (const float*)d_in[6];
  const float* b2    = (const float*)d_in[7];
  const float* Wl    = (const float*)d_in[8];
  const float* bl    = (const float*)d_in[9];
  float* out = (float*)d_out;

  const int N = in_sizes[0] / HDIM;     // 100000
  const int E = in_sizes[2];            // 1600000
  const int G = out_size / 2;           // 512

  const int* row = ei;
  const int* col = ei + E;

  // ---- workspace layout (256B aligned) ----
  auto al = [](size_t v) { return (v + 255) & ~(size_t)255; };
  char* ws = (char*)d_ws;
  size_t o_dc64   = 0;                                   // u64[N] (zeroed)
  size_t zero_end = o_dc64   + al((size_t)N * 8);
  size_t o_rank   = zero_end;                            // u16[E]
  size_t o_dis    = o_rank   + al((size_t)E * 2);        // f32[N]
  size_t o_start  = o_dis    + al((size_t)N * 4);        // i32[G+1]
  size_t o_off    = o_start  + al(((size_t)G + 1) * 4);  // i32[N+1]
  size_t o_part   = o_off    + al(((size_t)N + 1) * 4);  // i32[512]
  size_t o_csr    = o_part   + al(2048);                 // int2[E]
  size_t o_xw     = o_csr    + al((size_t)E * 8);        // fp16x2 uint[N*64]
  size_t o_h      = o_xw     + al((size_t)N * 64 * 4);   // fp16x2 uint[N*64]
  size_t o_pooled = o_h      + al((size_t)N * 64 * 4);   // f32[G*128]

  u64*   dc64    = (u64*)  (ws + o_dc64);
  unsigned short* rank = (unsigned short*)(ws + o_rank);
  float* dis     = (float*)(ws + o_dis);
  int*   start   = (int*)  (ws + o_start);
  int*   off     = (int*)  (ws + o_off);
  int*   part    = (int*)  (ws + o_part);
  int2*  csr     = (int2*) (ws + o_csr);
  uint*  xw      = (uint*) (ws + o_xw);
  uint*  hbuf    = (uint*) (ws + o_h);
  float* pooled  = (float*)(ws + o_pooled);

  hipMemsetAsync(ws, 0, zero_end, stream);

  int EB = (E + 255) / 256;   // 6250 hist blocks
  int NB = (N + 255) / 256;
  int nstrip = (N + 15) / 16;
  int MB = 1024;              // gemm blocks (grid-stride over strips)
  int AB = (N + 3) / 4;       // agg blocks (4 waves/block)

  // hist (atomic-bound) || gemm1 (MFMA-bound) in one dispatch
  hist_gemm1_kernel<<<EB + MB, 256, 0, stream>>>(
      col, ew, dc64, rank, E, EB, x, W1, xw, N, nstrip, MB);

  node_scan_kernel<<<NB, 256, 0, stream>>>(dc64, dis, batch, start, off, part, N, G);
  scan_part_kernel<<<1, 512, 0, stream>>>(part, NB);
  scan_add_kernel<<<NB, 256, 0, stream>>>(off, part, N, E);

  fill_kernel<<<EB, 256, 0, stream>>>(row, col, ew, rank, dis, off, csr, E);

  // layer 1 aggregate
  agg_kernel<<<AB, 256, 0, stream>>>(xw, csr, dis, off, b1, hbuf, N);

  // layer 2: xw2 = fp16(h1 @ W2) ; h2 = fp16(relu(agg(xw2) + b2))
  gemm_mfma_kernel<<<MB, 256, 0, stream>>>((const _Float16*)hbuf, W2, xw, N, nstrip);
  agg_kernel<<<AB, 256, 0, stream>>>(xw, csr, dis, off, b2, hbuf, N);

  // mean-pool per sorted-batch segment, then linear head
  pool_kernel<<<G, 64, 0, stream>>>(hbuf, start, pooled);
  final_kernel<<<G, 64, 0, stream>>>(pooled, Wl, bl, out);
}

// Round 7
// 292.621 us; speedup vs baseline: 3.3187x; 1.2670x over previous
//
#include <hip/hip_runtime.h>
#include <hip/hip_fp16.h>

// ---------------------------------------------------------------------------
// GCN graph classifier: 2x GCNConv(128->128) + global_mean_pool + Linear(128->2)
// R7: R6 with the gemm epilogue readback FIXED (4 passes x 16 lanes/row so all
// 256B of each staged row are read back and stored; R6 only covered 64B).
// W-staging via coalesced row-segments -> 16B LDS writes; epilogue staged in
// per-wave LDS -> 1KB contiguous wave stores; hist grid-stride with 4-deep
// atomic ILP; pool 4-way row-parallel.
// ---------------------------------------------------------------------------

#define HDIM 128
typedef unsigned int uint;
typedef unsigned long long u64;
typedef _Float16 half8 __attribute__((ext_vector_type(8)));
typedef float f32x4 __attribute__((ext_vector_type(4)));

// ---- gemm body: Y[n][128](fp16) = A[n][128] @ W[128][128](f32 global) ----
// Swapped operands: D = Wt * X^T per 16-row strip (layouts validated R4).
// smem: [0,32768) swizzled fp16 W^T; [32768 + wave*4096) epilogue staging.
template <typename AT>
__device__ __forceinline__ void gemm_body(
    const AT* __restrict__ A, const float* __restrict__ W, uint* __restrict__ Y,
    int n, int nstrip, int tid, int bid, int nblk, char* smem) {
  char* Wt = smem;
  // stage W^T as fp16 [c:128][k:128], byte ^= (c&7)<<4.
  // thread t: column c = t&127, k-octet k8 = t>>7; 8 coalesced row-segment
  // reads, one 16B LDS write (b128 bank floor).
  for (int t = tid; t < 2048; t += 256) {
    int c = t & 127;
    int k8 = t >> 7;
    const float* wp = W + (size_t)(k8 * 8) * HDIM + c;
    half8 hv;
#pragma unroll
    for (int m = 0; m < 8; ++m) hv[m] = (_Float16)wp[m * HDIM];
    int byte = c * 256 + k8 * 16;
    byte ^= ((c & 7) << 4);
    *(half8*)&Wt[byte] = hv;
  }
  __syncthreads();

  int wave = tid >> 6, lane = tid & 63;
  int l15 = lane & 15, l4 = lane >> 4;
  char* ep = smem + 32768 + wave * 4096;
  int stride = nblk * 4;
  for (int s = bid * 4 + wave; s < nstrip; s += stride) {
    int row0 = s << 4;
    int xrl = min(row0 + l15, n - 1);
    half8 bf[4];
    if constexpr (sizeof(AT) == 4) {
      const float* ap = (const float*)A + (size_t)xrl * HDIM + l4 * 8;
#pragma unroll
      for (int kk = 0; kk < 4; ++kk) {
        float4 u = *(const float4*)(ap + kk * 32);
        float4 v = *(const float4*)(ap + kk * 32 + 4);
        half8 h;
        h[0] = (_Float16)u.x; h[1] = (_Float16)u.y;
        h[2] = (_Float16)u.z; h[3] = (_Float16)u.w;
        h[4] = (_Float16)v.x; h[5] = (_Float16)v.y;
        h[6] = (_Float16)v.z; h[7] = (_Float16)v.w;
        bf[kk] = h;
      }
    } else {
      const half8* ap = (const half8*)((const _Float16*)A + (size_t)xrl * HDIM + l4 * 8);
#pragma unroll
      for (int kk = 0; kk < 4; ++kk) bf[kk] = ap[kk * 4];
    }
    f32x4 acc[8];
#pragma unroll
    for (int cf = 0; cf < 8; ++cf) acc[cf] = (f32x4){0.f, 0.f, 0.f, 0.f};
#pragma unroll
    for (int kk = 0; kk < 4; ++kk) {
#pragma unroll
      for (int cf = 0; cf < 8; ++cf) {
        int c = cf * 16 + l15;
        int byte = c * 256 + kk * 64 + l4 * 16;
        byte ^= ((c & 7) << 4);
        half8 af = *(half8*)&Wt[byte];
        acc[cf] = __builtin_amdgcn_mfma_f32_16x16x32_f16(af, bf[kk], acc[cf], 0, 0, 0);
      }
    }
    // epilogue: stage 16 fp16 rows (4KB) in per-wave LDS, read back coalesced.
    // write: row l15, logical bytes cf*32 + l4*8 (+8), swizzled by (row&7)<<4
#pragma unroll
    for (int cf = 0; cf < 8; ++cf) {
      __half2 p0 = __floats2half2_rn(acc[cf][0], acc[cf][1]);
      __half2 p1 = __floats2half2_rn(acc[cf][2], acc[cf][3]);
      int byte = l15 * 256 + cf * 32 + l4 * 8;
      byte ^= ((l15 & 7) << 4);
      *(uint2*)&ep[byte] = make_uint2(*(uint*)&p0, *(uint*)&p1);
    }
    asm volatile("s_waitcnt lgkmcnt(0)" ::: "memory");
    // readback: 4 passes, 16 lanes per row x 16B -> full 256B per row;
    // wave stores 1KB contiguous per pass.
#pragma unroll
    for (int p = 0; p < 4; ++p) {
      int rl = p * 4 + (lane >> 4);          // 0..15
      int byte = rl * 256 + (lane & 15) * 16;
      byte ^= ((rl & 7) << 4);
      uint4 v = *(uint4*)&ep[byte];
      int orow = row0 + rl;
      if (orow < n)
        *(uint4*)(Y + ((size_t)orow << 6) + (lane & 15) * 4) = v;
    }
  }
}

// K1 fused: blocks [0,MBg) run gemm1 (start immediately, MFMA/BW-bound);
// blocks [MBg,MBg+HB) run hist: grid-stride, 4 independent packed atomics
// in flight per thread (count in bits[40:63], ew 20.20 fixed in [0:39];
// returned old>>40 = edge's rank within its destination).
__global__ __launch_bounds__(256) void gemm1_hist_kernel(
    const float* __restrict__ A, const float* __restrict__ W,
    uint* __restrict__ Y, int n, int nstrip, int MBg,
    const int* __restrict__ col, const float* __restrict__ ew,
    u64* __restrict__ dc64, unsigned short* __restrict__ rank, int E, int HB) {
  __shared__ __align__(16) char smem[49152];
  int bid = blockIdx.x;
  if (bid < MBg) {
    gemm_body<float>(A, W, Y, n, nstrip, threadIdx.x, bid, MBg, smem);
    return;
  }
  int stride = HB * 256;
  for (int e = (bid - MBg) * 256 + threadIdx.x; e < E; e += 4 * stride) {
#pragma unroll
    for (int q = 0; q < 4; ++q) {
      int eq = e + q * stride;
      if (eq < E) {
        int c = col[eq];
        u64 pack = ((u64)1 << 40) + (u64)__float2uint_rn(ew[eq] * 1048576.0f);
        u64 old = atomicAdd(&dc64[c], pack);
        rank[eq] = (unsigned short)(old >> 40);
      }
    }
  }
}

// standalone gemm for layer 2 (fp16 A)
__global__ __launch_bounds__(256) void gemm_mfma_kernel(
    const _Float16* __restrict__ A, const float* __restrict__ W,
    uint* __restrict__ Y, int n, int nstrip) {
  __shared__ __align__(16) char smem[49152];
  gemm_body<_Float16>(A, W, Y, n, nstrip, threadIdx.x, blockIdx.x, gridDim.x, smem);
}

// K2: fused node unpack (dis, graph starts) + per-block scan of counts
__global__ __launch_bounds__(256) void node_scan_kernel(
    const u64* __restrict__ dc64, float* __restrict__ dis,
    const int* __restrict__ batch, int* __restrict__ start,
    int* __restrict__ off, int* __restrict__ part, int n, int G) {
  __shared__ int tmp[256];
  int tid = threadIdx.x;
  int i = blockIdx.x * 256 + tid;
  int v = 0;
  if (i < n) {
    u64 p = dc64[i];
    v = (int)(p >> 40);
    float deg = (float)(p & 0xFFFFFFFFFFull) * (1.0f / 1048576.0f);
    dis[i] = rsqrtf(deg + 1.0f);
    int b = batch[i];
    if (i == 0) {
      for (int h = 0; h <= b; ++h) start[h] = 0;
    } else {
      int bp = batch[i - 1];
      for (int h = bp + 1; h <= b; ++h) start[h] = i;
    }
    if (i == n - 1) {
      for (int h = b + 1; h <= G; ++h) start[h] = n;
    }
  }
  tmp[tid] = v;
  __syncthreads();
  for (int d = 1; d < 256; d <<= 1) {
    int t = (tid >= d) ? tmp[tid - d] : 0;
    __syncthreads();
    tmp[tid] += t;
    __syncthreads();
  }
  if (i < n) off[i] = tmp[tid] - v;       // exclusive
  if (tid == 255) part[blockIdx.x] = tmp[255];
}

// K3b: scan the block sums (single block, nb <= 512)
__global__ __launch_bounds__(512) void scan_part_kernel(int* part, int nb) {
  __shared__ int tmp[512];
  int tid = threadIdx.x;
  int v = (tid < nb) ? part[tid] : 0;
  tmp[tid] = v;
  __syncthreads();
  for (int d = 1; d < 512; d <<= 1) {
    int t = (tid >= d) ? tmp[tid - d] : 0;
    __syncthreads();
    tmp[tid] += t;
    __syncthreads();
  }
  if (tid < nb) part[tid] = tmp[tid] - v; // exclusive
}

// K3c: add block offsets; write sentinel off[n] = E
__global__ __launch_bounds__(256) void scan_add_kernel(
    int* __restrict__ off, const int* __restrict__ part, int n, int total) {
  int i = blockIdx.x * 256 + threadIdx.x;
  if (i < n) off[i] += part[blockIdx.x];
  if (i == 0) off[n] = total;
}

// K4: atomic-free CSR fill; norm = dis[row]*ew (dis[col] folded into agg)
__global__ __launch_bounds__(256) void fill_kernel(
    const int* __restrict__ row, const int* __restrict__ col,
    const float* __restrict__ ew, const unsigned short* __restrict__ rank,
    const float* __restrict__ dis, const int* __restrict__ off,
    int2* __restrict__ csr, int E) {
  int e = blockIdx.x * 256 + threadIdx.x;
  if (e < E) {
    int c = col[e];
    int r = row[e];
    int slot = off[c] + (int)rank[e];
    csr[slot] = make_int2(r, __float_as_int(dis[r] * ew[e]));
  }
}

// Aggregate (pull): one wave per node; lanes hold 2 features (one fp16x2 word).
// out = relu( dc*( sum_e nrm_e*xw[src_e] + dc*xw_self ) + bias ), fp16 out.
__global__ __launch_bounds__(256) void agg_kernel(
    const uint* __restrict__ xw, const int2* __restrict__ csr,
    const float* __restrict__ dis, const int* __restrict__ off,
    const float* __restrict__ bias, uint* __restrict__ out, int n) {
  int node = blockIdx.x * 4 + (threadIdx.x >> 6);
  if (node >= n) return;
  int lane = threadIdx.x & 63;
  const uint* xwl = xw + lane;
  float dc = dis[node];
  float ax, ay;
  {
    uint v = xwl[(size_t)node << 6];
    float2 f = __half22float2(*(const __half2*)&v);
    ax = dc * f.x;
    ay = dc * f.y;
  }
  int s = off[node], t = off[node + 1];
  int i = s;
  for (; i + 8 <= t; i += 8) {
    int2 e0 = csr[i],     e1 = csr[i + 1], e2 = csr[i + 2], e3 = csr[i + 3];
    int2 e4 = csr[i + 4], e5 = csr[i + 5], e6 = csr[i + 6], e7 = csr[i + 7];
    uint v0 = xwl[(size_t)e0.x << 6];
    uint v1 = xwl[(size_t)e1.x << 6];
    uint v2 = xwl[(size_t)e2.x << 6];
    uint v3 = xwl[(size_t)e3.x << 6];
    uint v4 = xwl[(size_t)e4.x << 6];
    uint v5 = xwl[(size_t)e5.x << 6];
    uint v6 = xwl[(size_t)e6.x << 6];
    uint v7 = xwl[(size_t)e7.x << 6];
    float2 f0 = __half22float2(*(const __half2*)&v0);
    float2 f1 = __half22float2(*(const __half2*)&v1);
    float2 f2 = __half22float2(*(const __half2*)&v2);
    float2 f3 = __half22float2(*(const __half2*)&v3);
    float2 f4 = __half22float2(*(const __half2*)&v4);
    float2 f5 = __half22float2(*(const __half2*)&v5);
    float2 f6 = __half22float2(*(const __half2*)&v6);
    float2 f7 = __half22float2(*(const __half2*)&v7);
    ax += __int_as_float(e0.y) * f0.x; ay += __int_as_float(e0.y) * f0.y;
    ax += __int_as_float(e1.y) * f1.x; ay += __int_as_float(e1.y) * f1.y;
    ax += __int_as_float(e2.y) * f2.x; ay += __int_as_float(e2.y) * f2.y;
    ax += __int_as_float(e3.y) * f3.x; ay += __int_as_float(e3.y) * f3.y;
    ax += __int_as_float(e4.y) * f4.x; ay += __int_as_float(e4.y) * f4.y;
    ax += __int_as_float(e5.y) * f5.x; ay += __int_as_float(e5.y) * f5.y;
    ax += __int_as_float(e6.y) * f6.x; ay += __int_as_float(e6.y) * f6.y;
    ax += __int_as_float(e7.y) * f7.x; ay += __int_as_float(e7.y) * f7.y;
  }
  for (; i + 4 <= t; i += 4) {
    int2 e0 = csr[i], e1 = csr[i + 1], e2 = csr[i + 2], e3 = csr[i + 3];
    uint v0 = xwl[(size_t)e0.x << 6];
    uint v1 = xwl[(size_t)e1.x << 6];
    uint v2 = xwl[(size_t)e2.x << 6];
    uint v3 = xwl[(size_t)e3.x << 6];
    float2 f0 = __half22float2(*(const __half2*)&v0);
    float2 f1 = __half22float2(*(const __half2*)&v1);
    float2 f2 = __half22float2(*(const __half2*)&v2);
    float2 f3 = __half22float2(*(const __half2*)&v3);
    ax += __int_as_float(e0.y) * f0.x; ay += __int_as_float(e0.y) * f0.y;
    ax += __int_as_float(e1.y) * f1.x; ay += __int_as_float(e1.y) * f1.y;
    ax += __int_as_float(e2.y) * f2.x; ay += __int_as_float(e2.y) * f2.y;
    ax += __int_as_float(e3.y) * f3.x; ay += __int_as_float(e3.y) * f3.y;
  }
  for (; i < t; ++i) {
    int2 e = csr[i];
    uint v = xwl[(size_t)e.x << 6];
    float2 f = __half22float2(*(const __half2*)&v);
    float nn = __int_as_float(e.y);
    ax += nn * f.x;
    ay += nn * f.y;
  }
  float2 b = *(const float2*)(bias + lane * 2);
  ax = fmaxf(dc * ax + b.x, 0.0f);
  ay = fmaxf(dc * ay + b.y, 0.0f);
  __half2 p = __floats2half2_rn(ax, ay);
  out[((size_t)node << 6) + lane] = *(uint*)&p;
}

// Mean-pool over sorted batch segments: 256 threads, 4 row-groups + LDS reduce.
__global__ __launch_bounds__(256) void pool_kernel(
    const uint* __restrict__ h, const int* __restrict__ start,
    float* __restrict__ pooled) {
  __shared__ float2 red[256];
  int g = blockIdx.x;
  int grp = threadIdx.x >> 6, f = threadIdx.x & 63;
  int s = start[g], e = start[g + 1];
  float s0 = 0.0f, s1 = 0.0f;
  for (int r = s + grp; r < e; r += 4) {
    uint v = h[((size_t)r << 6) + f];
    float2 fv = __half22float2(*(const __half2*)&v);
    s0 += fv.x;
    s1 += fv.y;
  }
  red[threadIdx.x] = make_float2(s0, s1);
  __syncthreads();
  if (grp == 0) {
    float2 a = red[f], b = red[64 + f], c = red[128 + f], d = red[192 + f];
    float inv = 1.0f / (float)max(e - s, 1);
    pooled[g * HDIM + 2 * f]     = (a.x + b.x + c.x + d.x) * inv;
    pooled[g * HDIM + 2 * f + 1] = (a.y + b.y + c.y + d.y) * inv;
  }
}

// Final: out[g][o] = dot(pooled[g], Wl[:,o]) + bl[o]
__global__ __launch_bounds__(64) void final_kernel(
    const float* __restrict__ pooled, const float* __restrict__ Wl,
    const float* __restrict__ bl, float* __restrict__ out) {
  int g = blockIdx.x;
  int lane = threadIdx.x;
  float p0 = pooled[g * HDIM + lane];
  float p1 = pooled[g * HDIM + 64 + lane];
#pragma unroll
  for (int o = 0; o < 2; ++o) {
    float s = p0 * Wl[lane * 2 + o] + p1 * Wl[(64 + lane) * 2 + o];
    for (int d = 32; d > 0; d >>= 1) s += __shfl_down(s, d);
    if (lane == 0) out[g * 2 + o] = s + bl[o];
  }
}

extern "C" void kernel_launch(void* const* d_in, const int* in_sizes, int n_in,
                              void* d_out, int out_size, void* d_ws, size_t ws_size,
                              hipStream_t stream) {
  const float* x     = (const float*)d_in[0];
  const int*   ei    = (const int*)d_in[1];
  const float* ew    = (const float*)d_in[2];
  const int*   batch = (const int*)d_in[3];
  const float* W1    = (const float*)d_in[4];
  const float* b1    = (const float*)d_in[5];
  const float* W2    = (const float*)d_in[6];
  const float* b2    = (const float*)d_in[7];
  const float* Wl    = (const float*)d_in[8];
  const float* bl    = (const float*)d_in[9];
  float* out = (float*)d_out;

  const int N = in_sizes[0] / HDIM;     // 100000
  const int E = in_sizes[2];            // 1600000
  const int G = out_size / 2;           // 512

  const int* row = ei;
  const int* col = ei + E;

  // ---- workspace layout (256B aligned) ----
  auto al = [](size_t v) { return (v + 255) & ~(size_t)255; };
  char* ws = (char*)d_ws;
  size_t o_dc64   = 0;                                   // u64[N] (zeroed)
  size_t zero_end = o_dc64   + al((size_t)N * 8);
  size_t o_rank   = zero_end;                            // u16[E]
  size_t o_dis    = o_rank   + al((size_t)E * 2);        // f32[N]
  size_t o_start  = o_dis    + al((size_t)N * 4);        // i32[G+1]
  size_t o_off    = o_start  + al(((size_t)G + 1) * 4);  // i32[N+1]
  size_t o_part   = o_off    + al(((size_t)N + 1) * 4);  // i32[512]
  size_t o_csr    = o_part   + al(2048);                 // int2[E]
  size_t o_xw     = o_csr    + al((size_t)E * 8);        // fp16x2 uint[N*64]
  size_t o_h      = o_xw     + al((size_t)N * 64 * 4);   // fp16x2 uint[N*64]
  size_t o_pooled = o_h      + al((size_t)N * 64 * 4);   // f32[G*128]

  u64*   dc64    = (u64*)  (ws + o_dc64);
  unsigned short* rank = (unsigned short*)(ws + o_rank);
  float* dis     = (float*)(ws + o_dis);
  int*   start   = (int*)  (ws + o_start);
  int*   off     = (int*)  (ws + o_off);
  int*   part    = (int*)  (ws + o_part);
  int2*  csr     = (int2*) (ws + o_csr);
  uint*  xw      = (uint*) (ws + o_xw);
  uint*  hbuf    = (uint*) (ws + o_h);
  float* pooled  = (float*)(ws + o_pooled);

  hipMemsetAsync(ws, 0, zero_end, stream);

  int EB = (E + 255) / 256;
  int NB = (N + 255) / 256;
  int nstrip = (N + 15) / 16;
  int MBg = 1024;             // gemm blocks in fused kernel
  int HB  = 1024;             // hist blocks (grid-stride, 4-deep atomic ILP)
  int MB  = 1024;             // gemm2 blocks
  int AB  = (N + 3) / 4;      // agg blocks (4 waves/block)

  // gemm1 (MFMA/BW-bound) || hist (atomic-bound) in one dispatch
  gemm1_hist_kernel<<<MBg + HB, 256, 0, stream>>>(
      x, W1, xw, N, nstrip, MBg, col, ew, dc64, rank, E, HB);

  node_scan_kernel<<<NB, 256, 0, stream>>>(dc64, dis, batch, start, off, part, N, G);
  scan_part_kernel<<<1, 512, 0, stream>>>(part, NB);
  scan_add_kernel<<<NB, 256, 0, stream>>>(off, part, N, E);

  fill_kernel<<<EB, 256, 0, stream>>>(row, col, ew, rank, dis, off, csr, E);

  // layer 1 aggregate
  agg_kernel<<<AB, 256, 0, stream>>>(xw, csr, dis, off, b1, hbuf, N);

  // layer 2: xw2 = fp16(h1 @ W2) ; h2 = fp16(relu(agg(xw2) + b2))
  gemm_mfma_kernel<<<MB, 256, 0, stream>>>((const _Float16*)hbuf, W2, xw, N, nstrip);
  agg_kernel<<<AB, 256, 0, stream>>>(xw, csr, dis, off, b2, hbuf, N);

  // mean-pool per sorted-batch segment, then linear head
  pool_kernel<<<G, 256, 0, stream>>>(hbuf, start, pooled);
  final_kernel<<<G, 64, 0, stream>>>(pooled, Wl, bl, out);
}

// Round 8
// 290.414 us; speedup vs baseline: 3.3439x; 1.0076x over previous
//
#include <hip/hip_runtime.h>
#include <hip/hip_fp16.h>

// ---------------------------------------------------------------------------
// GCN graph classifier: 2x GCNConv(128->128) + global_mean_pool + Linear(128->2)
// R8: fused gemm1||hist with INTERLEAVED block roles (parity) so both are
// co-resident (R7 serialized by dispatch order). Dual-edge half-wave agg:
// 8B/lane gathers, 2 edge rows per instruction, parity combine via shfl_xor.
// rank stored as u8.
// ---------------------------------------------------------------------------

#define HDIM 128
typedef unsigned int uint;
typedef unsigned long long u64;
typedef _Float16 half8 __attribute__((ext_vector_type(8)));
typedef float f32x4 __attribute__((ext_vector_type(4)));

// ---- gemm body: Y[n][128](fp16) = A[n][128] @ W[128][128](f32 global) ----
// Swapped operands: D = Wt * X^T per 16-row strip (layouts validated R4/R7).
// smem: [0,32768) swizzled fp16 W^T; [32768 + wave*4096) epilogue staging.
template <typename AT>
__device__ __forceinline__ void gemm_body(
    const AT* __restrict__ A, const float* __restrict__ W, uint* __restrict__ Y,
    int n, int nstrip, int tid, int bid, int nblk, char* smem) {
  char* Wt = smem;
  for (int t = tid; t < 2048; t += 256) {
    int c = t & 127;
    int k8 = t >> 7;
    const float* wp = W + (size_t)(k8 * 8) * HDIM + c;
    half8 hv;
#pragma unroll
    for (int m = 0; m < 8; ++m) hv[m] = (_Float16)wp[m * HDIM];
    int byte = c * 256 + k8 * 16;
    byte ^= ((c & 7) << 4);
    *(half8*)&Wt[byte] = hv;
  }
  __syncthreads();

  int wave = tid >> 6, lane = tid & 63;
  int l15 = lane & 15, l4 = lane >> 4;
  char* ep = smem + 32768 + wave * 4096;
  int stride = nblk * 4;
  for (int s = bid * 4 + wave; s < nstrip; s += stride) {
    int row0 = s << 4;
    int xrl = min(row0 + l15, n - 1);
    half8 bf[4];
    if constexpr (sizeof(AT) == 4) {
      const float* ap = (const float*)A + (size_t)xrl * HDIM + l4 * 8;
#pragma unroll
      for (int kk = 0; kk < 4; ++kk) {
        float4 u = *(const float4*)(ap + kk * 32);
        float4 v = *(const float4*)(ap + kk * 32 + 4);
        half8 h;
        h[0] = (_Float16)u.x; h[1] = (_Float16)u.y;
        h[2] = (_Float16)u.z; h[3] = (_Float16)u.w;
        h[4] = (_Float16)v.x; h[5] = (_Float16)v.y;
        h[6] = (_Float16)v.z; h[7] = (_Float16)v.w;
        bf[kk] = h;
      }
    } else {
      const half8* ap = (const half8*)((const _Float16*)A + (size_t)xrl * HDIM + l4 * 8);
#pragma unroll
      for (int kk = 0; kk < 4; ++kk) bf[kk] = ap[kk * 4];
    }
    f32x4 acc[8];
#pragma unroll
    for (int cf = 0; cf < 8; ++cf) acc[cf] = (f32x4){0.f, 0.f, 0.f, 0.f};
#pragma unroll
    for (int kk = 0; kk < 4; ++kk) {
#pragma unroll
      for (int cf = 0; cf < 8; ++cf) {
        int c = cf * 16 + l15;
        int byte = c * 256 + kk * 64 + l4 * 16;
        byte ^= ((c & 7) << 4);
        half8 af = *(half8*)&Wt[byte];
        acc[cf] = __builtin_amdgcn_mfma_f32_16x16x32_f16(af, bf[kk], acc[cf], 0, 0, 0);
      }
    }
#pragma unroll
    for (int cf = 0; cf < 8; ++cf) {
      __half2 p0 = __floats2half2_rn(acc[cf][0], acc[cf][1]);
      __half2 p1 = __floats2half2_rn(acc[cf][2], acc[cf][3]);
      int byte = l15 * 256 + cf * 32 + l4 * 8;
      byte ^= ((l15 & 7) << 4);
      *(uint2*)&ep[byte] = make_uint2(*(uint*)&p0, *(uint*)&p1);
    }
    asm volatile("s_waitcnt lgkmcnt(0)" ::: "memory");
#pragma unroll
    for (int p = 0; p < 4; ++p) {
      int rl = p * 4 + (lane >> 4);          // 0..15
      int byte = rl * 256 + (lane & 15) * 16;
      byte ^= ((rl & 7) << 4);
      uint4 v = *(uint4*)&ep[byte];
      int orow = row0 + rl;
      if (orow < n)
        *(uint4*)(Y + ((size_t)orow << 6) + (lane & 15) * 4) = v;
    }
  }
}

// K1 fused, INTERLEAVED roles: even blocks hist, odd blocks gemm1.
// hist: grid-stride, 4 independent packed atomics in flight per thread
// (count in bits[40:63], ew 20.20 fixed in [0:39]; old>>40 = rank).
__global__ __launch_bounds__(256) void gemm1_hist_kernel(
    const float* __restrict__ A, const float* __restrict__ W,
    uint* __restrict__ Y, int n, int nstrip, int MBg,
    const int* __restrict__ col, const float* __restrict__ ew,
    u64* __restrict__ dc64, unsigned char* __restrict__ rank, int E, int HB) {
  __shared__ __align__(16) char smem[49152];
  int bid = blockIdx.x;
  if (bid & 1) {
    gemm_body<float>(A, W, Y, n, nstrip, threadIdx.x, bid >> 1, MBg, smem);
    return;
  }
  int stride = HB * 256;
  for (int e = (bid >> 1) * 256 + threadIdx.x; e < E; e += 4 * stride) {
#pragma unroll
    for (int q = 0; q < 4; ++q) {
      int eq = e + q * stride;
      if (eq < E) {
        int c = col[eq];
        u64 pack = ((u64)1 << 40) + (u64)__float2uint_rn(ew[eq] * 1048576.0f);
        u64 old = atomicAdd(&dc64[c], pack);
        rank[eq] = (unsigned char)(old >> 40);
      }
    }
  }
}

// standalone gemm for layer 2 (fp16 A)
__global__ __launch_bounds__(256) void gemm_mfma_kernel(
    const _Float16* __restrict__ A, const float* __restrict__ W,
    uint* __restrict__ Y, int n, int nstrip) {
  __shared__ __align__(16) char smem[49152];
  gemm_body<_Float16>(A, W, Y, n, nstrip, threadIdx.x, blockIdx.x, gridDim.x, smem);
}

// K2: fused node unpack (dis, graph starts) + per-block scan of counts
__global__ __launch_bounds__(256) void node_scan_kernel(
    const u64* __restrict__ dc64, float* __restrict__ dis,
    const int* __restrict__ batch, int* __restrict__ start,
    int* __restrict__ off, int* __restrict__ part, int n, int G) {
  __shared__ int tmp[256];
  int tid = threadIdx.x;
  int i = blockIdx.x * 256 + tid;
  int v = 0;
  if (i < n) {
    u64 p = dc64[i];
    v = (int)(p >> 40);
    float deg = (float)(p & 0xFFFFFFFFFFull) * (1.0f / 1048576.0f);
    dis[i] = rsqrtf(deg + 1.0f);
    int b = batch[i];
    if (i == 0) {
      for (int h = 0; h <= b; ++h) start[h] = 0;
    } else {
      int bp = batch[i - 1];
      for (int h = bp + 1; h <= b; ++h) start[h] = i;
    }
    if (i == n - 1) {
      for (int h = b + 1; h <= G; ++h) start[h] = n;
    }
  }
  tmp[tid] = v;
  __syncthreads();
  for (int d = 1; d < 256; d <<= 1) {
    int t = (tid >= d) ? tmp[tid - d] : 0;
    __syncthreads();
    tmp[tid] += t;
    __syncthreads();
  }
  if (i < n) off[i] = tmp[tid] - v;       // exclusive
  if (tid == 255) part[blockIdx.x] = tmp[255];
}

// K3b: scan the block sums (single block, nb <= 512)
__global__ __launch_bounds__(512) void scan_part_kernel(int* part, int nb) {
  __shared__ int tmp[512];
  int tid = threadIdx.x;
  int v = (tid < nb) ? part[tid] : 0;
  tmp[tid] = v;
  __syncthreads();
  for (int d = 1; d < 512; d <<= 1) {
    int t = (tid >= d) ? tmp[tid - d] : 0;
    __syncthreads();
    tmp[tid] += t;
    __syncthreads();
  }
  if (tid < nb) part[tid] = tmp[tid] - v; // exclusive
}

// K3c: add block offsets; write sentinel off[n] = E
__global__ __launch_bounds__(256) void scan_add_kernel(
    int* __restrict__ off, const int* __restrict__ part, int n, int total) {
  int i = blockIdx.x * 256 + threadIdx.x;
  if (i < n) off[i] += part[blockIdx.x];
  if (i == 0) off[n] = total;
}

// K4: atomic-free CSR fill; norm = dis[row]*ew (dis[col] folded into agg)
__global__ __launch_bounds__(256) void fill_kernel(
    const int* __restrict__ row, const int* __restrict__ col,
    const float* __restrict__ ew, const unsigned char* __restrict__ rank,
    const float* __restrict__ dis, const int* __restrict__ off,
    int2* __restrict__ csr, int E) {
  int e = blockIdx.x * 256 + threadIdx.x;
  if (e < E) {
    int c = col[e];
    int r = row[e];
    int slot = off[c] + (int)rank[e];
    csr[slot] = make_int2(r, __float_as_int(dis[r] * ew[e]));
  }
}

// Aggregate (pull), dual-edge half-wave: lane = (par:1)(hl:5); lane loads
// uint2 = 4 fp16 features of edge (i+par)'s source row; 32 lanes cover the
// 256B row, wave gathers 2 rows/instruction. Parities combined via shfl_xor.
// out = relu( dc*( sum_e nrm_e*xw[src_e] + dc*xw_self ) + bias ), fp16 out.
__global__ __launch_bounds__(256) void agg_kernel(
    const uint* __restrict__ xw, const int2* __restrict__ csr,
    const float* __restrict__ dis, const int* __restrict__ off,
    const float* __restrict__ bias, uint* __restrict__ out, int n) {
  int node = blockIdx.x * 4 + (threadIdx.x >> 6);
  if (node >= n) return;
  int lane = threadIdx.x & 63;
  int hl = lane & 31;          // feature group: features 4*hl .. 4*hl+3
  int par = lane >> 5;         // edge parity
  const uint2* xw2 = (const uint2*)xw;
  float dc = dis[node];
  float a0, a1, a2, a3;
  {
    uint2 v = xw2[((size_t)node << 5) + hl];
    float2 lo = __half22float2(*(const __half2*)&v.x);
    float2 hi = __half22float2(*(const __half2*)&v.y);
    float sd = (par == 0) ? dc : 0.0f;   // self term counted once
    a0 = sd * lo.x; a1 = sd * lo.y; a2 = sd * hi.x; a3 = sd * hi.y;
  }
  int s = off[node], t = off[node + 1];
  int i = s;
  for (; i + 8 <= t; i += 8) {           // 4 edges per lane-parity
    int2 e0 = csr[i + par];
    int2 e1 = csr[i + 2 + par];
    int2 e2 = csr[i + 4 + par];
    int2 e3 = csr[i + 6 + par];
    uint2 v0 = xw2[((size_t)e0.x << 5) + hl];
    uint2 v1 = xw2[((size_t)e1.x << 5) + hl];
    uint2 v2 = xw2[((size_t)e2.x << 5) + hl];
    uint2 v3 = xw2[((size_t)e3.x << 5) + hl];
    float n0 = __int_as_float(e0.y), n1 = __int_as_float(e1.y);
    float n2 = __int_as_float(e2.y), n3 = __int_as_float(e3.y);
    float2 l0 = __half22float2(*(const __half2*)&v0.x);
    float2 h0 = __half22float2(*(const __half2*)&v0.y);
    float2 l1 = __half22float2(*(const __half2*)&v1.x);
    float2 h1 = __half22float2(*(const __half2*)&v1.y);
    float2 l2 = __half22float2(*(const __half2*)&v2.x);
    float2 h2 = __half22float2(*(const __half2*)&v2.y);
    float2 l3 = __half22float2(*(const __half2*)&v3.x);
    float2 h3 = __half22float2(*(const __half2*)&v3.y);
    a0 += n0 * l0.x; a1 += n0 * l0.y; a2 += n0 * h0.x; a3 += n0 * h0.y;
    a0 += n1 * l1.x; a1 += n1 * l1.y; a2 += n1 * h1.x; a3 += n1 * h1.y;
    a0 += n2 * l2.x; a1 += n2 * l2.y; a2 += n2 * h2.x; a3 += n2 * h2.y;
    a0 += n3 * l3.x; a1 += n3 * l3.y; a2 += n3 * h3.x; a3 += n3 * h3.y;
  }
  for (; i < t; i += 2) {                // tail: up to 1 edge per parity
    if (i + par < t) {
      int2 e = csr[i + par];
      uint2 v = xw2[((size_t)e.x << 5) + hl];
      float nn = __int_as_float(e.y);
      float2 lo = __half22float2(*(const __half2*)&v.x);
      float2 hi = __half22float2(*(const __half2*)&v.y);
      a0 += nn * lo.x; a1 += nn * lo.y; a2 += nn * hi.x; a3 += nn * hi.y;
    }
  }
  // combine parities
  a0 += __shfl_xor(a0, 32);
  a1 += __shfl_xor(a1, 32);
  a2 += __shfl_xor(a2, 32);
  a3 += __shfl_xor(a3, 32);
  if (par == 0) {
    float4 b = *(const float4*)(bias + hl * 4);
    a0 = fmaxf(dc * a0 + b.x, 0.0f);
    a1 = fmaxf(dc * a1 + b.y, 0.0f);
    a2 = fmaxf(dc * a2 + b.z, 0.0f);
    a3 = fmaxf(dc * a3 + b.w, 0.0f);
    __half2 p0 = __floats2half2_rn(a0, a1);
    __half2 p1 = __floats2half2_rn(a2, a3);
    ((uint2*)out)[((size_t)node << 5) + hl] = make_uint2(*(uint*)&p0, *(uint*)&p1);
  }
}

// Mean-pool over sorted batch segments: 256 threads, 4 row-groups + LDS reduce.
__global__ __launch_bounds__(256) void pool_kernel(
    const uint* __restrict__ h, const int* __restrict__ start,
    float* __restrict__ pooled) {
  __shared__ float2 red[256];
  int g = blockIdx.x;
  int grp = threadIdx.x >> 6, f = threadIdx.x & 63;
  int s = start[g], e = start[g + 1];
  float s0 = 0.0f, s1 = 0.0f;
  for (int r = s + grp; r < e; r += 4) {
    uint v = h[((size_t)r << 6) + f];
    float2 fv = __half22float2(*(const __half2*)&v);
    s0 += fv.x;
    s1 += fv.y;
  }
  red[threadIdx.x] = make_float2(s0, s1);
  __syncthreads();
  if (grp == 0) {
    float2 a = red[f], b = red[64 + f], c = red[128 + f], d = red[192 + f];
    float inv = 1.0f / (float)max(e - s, 1);
    pooled[g * HDIM + 2 * f]     = (a.x + b.x + c.x + d.x) * inv;
    pooled[g * HDIM + 2 * f + 1] = (a.y + b.y + c.y + d.y) * inv;
  }
}

// Final: out[g][o] = dot(pooled[g], Wl[:,o]) + bl[o]
__global__ __launch_bounds__(64) void final_kernel(
    const float* __restrict__ pooled, const float* __restrict__ Wl,
    const float* __restrict__ bl, float* __restrict__ out) {
  int g = blockIdx.x;
  int lane = threadIdx.x;
  float p0 = pooled[g * HDIM + lane];
  float p1 = pooled[g * HDIM + 64 + lane];
#pragma unroll
  for (int o = 0; o < 2; ++o) {
    float s = p0 * Wl[lane * 2 + o] + p1 * Wl[(64 + lane) * 2 + o];
    for (int d = 32; d > 0; d >>= 1) s += __shfl_down(s, d);
    if (lane == 0) out[g * 2 + o] = s + bl[o];
  }
}

extern "C" void kernel_launch(void* const* d_in, const int* in_sizes, int n_in,
                              void* d_out, int out_size, void* d_ws, size_t ws_size,
                              hipStream_t stream) {
  const float* x     = (const float*)d_in[0];
  const int*   ei    = (const int*)d_in[1];
  const float* ew    = (const float*)d_in[2];
  const int*   batch = (const int*)d_in[3];
  const float* W1    = (const float*)d_in[4];
  const float* b1    = (const float*)d_in[5];
  const float* W2    = (const float*)d_in[6];
  const float* b2    = (const float*)d_in[7];
  const float* Wl    = (const float*)d_in[8];
  const float* bl    = (const float*)d_in[9];
  float* out = (float*)d_out;

  const int N = in_sizes[0] / HDIM;     // 100000
  const int E = in_sizes[2];            // 1600000
  const int G = out_size / 2;           // 512

  const int* row = ei;
  const int* col = ei + E;

  // ---- workspace layout (256B aligned) ----
  auto al = [](size_t v) { return (v + 255) & ~(size_t)255; };
  char* ws = (char*)d_ws;
  size_t o_dc64   = 0;                                   // u64[N] (zeroed)
  size_t zero_end = o_dc64   + al((size_t)N * 8);
  size_t o_rank   = zero_end;                            // u8[E]
  size_t o_dis    = o_rank   + al((size_t)E);            // f32[N]
  size_t o_start  = o_dis    + al((size_t)N * 4);        // i32[G+1]
  size_t o_off    = o_start  + al(((size_t)G + 1) * 4);  // i32[N+1]
  size_t o_part   = o_off    + al(((size_t)N + 1) * 4);  // i32[512]
  size_t o_csr    = o_part   + al(2048);                 // int2[E]
  size_t o_xw     = o_csr    + al((size_t)E * 8);        // fp16x2 uint[N*64]
  size_t o_h      = o_xw     + al((size_t)N * 64 * 4);   // fp16x2 uint[N*64]
  size_t o_pooled = o_h      + al((size_t)N * 64 * 4);   // f32[G*128]

  u64*   dc64    = (u64*)  (ws + o_dc64);
  unsigned char* rank = (unsigned char*)(ws + o_rank);
  float* dis     = (float*)(ws + o_dis);
  int*   start   = (int*)  (ws + o_start);
  int*   off     = (int*)  (ws + o_off);
  int*   part    = (int*)  (ws + o_part);
  int2*  csr     = (int2*) (ws + o_csr);
  uint*  xw      = (uint*) (ws + o_xw);
  uint*  hbuf    = (uint*) (ws + o_h);
  float* pooled  = (float*)(ws + o_pooled);

  hipMemsetAsync(ws, 0, zero_end, stream);

  int EB = (E + 255) / 256;
  int NB = (N + 255) / 256;
  int nstrip = (N + 15) / 16;
  int MBg = 1024;             // gemm blocks in fused kernel (odd bids)
  int HB  = 1024;             // hist blocks (even bids, 4-deep atomic ILP)
  int MB  = 1024;             // gemm2 blocks
  int AB  = (N + 3) / 4;      // agg blocks (4 waves/block)

  // hist (atomic-bound) || gemm1 (MFMA/BW-bound), roles interleaved by parity
  gemm1_hist_kernel<<<MBg + HB, 256, 0, stream>>>(
      x, W1, xw, N, nstrip, MBg, col, ew, dc64, rank, E, HB);

  node_scan_kernel<<<NB, 256, 0, stream>>>(dc64, dis, batch, start, off, part, N, G);
  scan_part_kernel<<<1, 512, 0, stream>>>(part, NB);
  scan_add_kernel<<<NB, 256, 0, stream>>>(off, part, N, E);

  fill_kernel<<<EB, 256, 0, stream>>>(row, col, ew, rank, dis, off, csr, E);

  // layer 1 aggregate
  agg_kernel<<<AB, 256, 0, stream>>>(xw, csr, dis, off, b1, hbuf, N);

  // layer 2: xw2 = fp16(h1 @ W2) ; h2 = fp16(relu(agg(xw2) + b2))
  gemm_mfma_kernel<<<MB, 256, 0, stream>>>((const _Float16*)hbuf, W2, xw, N, nstrip);
  agg_kernel<<<AB, 256, 0, stream>>>(xw, csr, dis, off, b2, hbuf, N);

  // mean-pool per sorted-batch segment, then linear head
  pool_kernel<<<G, 256, 0, stream>>>(hbuf, start, pooled);
  final_kernel<<<G, 64, 0, stream>>>(pooled, Wl, bl, out);
}

// Round 9
// 277.601 us; speedup vs baseline: 3.4983x; 1.0462x over previous
//
#include <hip/hip_runtime.h>
#include <hip/hip_fp16.h>

// ---------------------------------------------------------------------------
// GCN graph classifier: 2x GCNConv(128->128) + global_mean_pool + Linear(128->2)
// R9: hist atomic shrunk to u32 (count<<26 | ew*2^16) with bins padded to 16B
// stride (tests op-width vs line-serialization bound). CSR packed to u32
// (row<<15 | q15 norm). Fused gemm1||hist parity-interleaved (R8), dual-edge
// half-wave agg, atomic-free fill, sorted-batch pooling.
// ---------------------------------------------------------------------------

#define HDIM 128
typedef unsigned int uint;
typedef _Float16 half8 __attribute__((ext_vector_type(8)));
typedef float f32x4 __attribute__((ext_vector_type(4)));

// ---- gemm body: Y[n][128](fp16) = A[n][128] @ W[128][128](f32 global) ----
// Swapped operands: D = Wt * X^T per 16-row strip (layouts validated R4/R7).
// smem: [0,32768) swizzled fp16 W^T; [32768 + wave*4096) epilogue staging.
template <typename AT>
__device__ __forceinline__ void gemm_body(
    const AT* __restrict__ A, const float* __restrict__ W, uint* __restrict__ Y,
    int n, int nstrip, int tid, int bid, int nblk, char* smem) {
  char* Wt = smem;
  for (int t = tid; t < 2048; t += 256) {
    int c = t & 127;
    int k8 = t >> 7;
    const float* wp = W + (size_t)(k8 * 8) * HDIM + c;
    half8 hv;
#pragma unroll
    for (int m = 0; m < 8; ++m) hv[m] = (_Float16)wp[m * HDIM];
    int byte = c * 256 + k8 * 16;
    byte ^= ((c & 7) << 4);
    *(half8*)&Wt[byte] = hv;
  }
  __syncthreads();

  int wave = tid >> 6, lane = tid & 63;
  int l15 = lane & 15, l4 = lane >> 4;
  char* ep = smem + 32768 + wave * 4096;
  int stride = nblk * 4;
  for (int s = bid * 4 + wave; s < nstrip; s += stride) {
    int row0 = s << 4;
    int xrl = min(row0 + l15, n - 1);
    half8 bf[4];
    if constexpr (sizeof(AT) == 4) {
      const float* ap = (const float*)A + (size_t)xrl * HDIM + l4 * 8;
#pragma unroll
      for (int kk = 0; kk < 4; ++kk) {
        float4 u = *(const float4*)(ap + kk * 32);
        float4 v = *(const float4*)(ap + kk * 32 + 4);
        half8 h;
        h[0] = (_Float16)u.x; h[1] = (_Float16)u.y;
        h[2] = (_Float16)u.z; h[3] = (_Float16)u.w;
        h[4] = (_Float16)v.x; h[5] = (_Float16)v.y;
        h[6] = (_Float16)v.z; h[7] = (_Float16)v.w;
        bf[kk] = h;
      }
    } else {
      const half8* ap = (const half8*)((const _Float16*)A + (size_t)xrl * HDIM + l4 * 8);
#pragma unroll
      for (int kk = 0; kk < 4; ++kk) bf[kk] = ap[kk * 4];
    }
    f32x4 acc[8];
#pragma unroll
    for (int cf = 0; cf < 8; ++cf) acc[cf] = (f32x4){0.f, 0.f, 0.f, 0.f};
#pragma unroll
    for (int kk = 0; kk < 4; ++kk) {
#pragma unroll
      for (int cf = 0; cf < 8; ++cf) {
        int c = cf * 16 + l15;
        int byte = c * 256 + kk * 64 + l4 * 16;
        byte ^= ((c & 7) << 4);
        half8 af = *(half8*)&Wt[byte];
        acc[cf] = __builtin_amdgcn_mfma_f32_16x16x32_f16(af, bf[kk], acc[cf], 0, 0, 0);
      }
    }
#pragma unroll
    for (int cf = 0; cf < 8; ++cf) {
      __half2 p0 = __floats2half2_rn(acc[cf][0], acc[cf][1]);
      __half2 p1 = __floats2half2_rn(acc[cf][2], acc[cf][3]);
      int byte = l15 * 256 + cf * 32 + l4 * 8;
      byte ^= ((l15 & 7) << 4);
      *(uint2*)&ep[byte] = make_uint2(*(uint*)&p0, *(uint*)&p1);
    }
    asm volatile("s_waitcnt lgkmcnt(0)" ::: "memory");
#pragma unroll
    for (int p = 0; p < 4; ++p) {
      int rl = p * 4 + (lane >> 4);          // 0..15
      int byte = rl * 256 + (lane & 15) * 16;
      byte ^= ((rl & 7) << 4);
      uint4 v = *(uint4*)&ep[byte];
      int orow = row0 + rl;
      if (orow < n)
        *(uint4*)(Y + ((size_t)orow << 6) + (lane & 15) * 4) = v;
    }
  }
}

// K1 fused, interleaved roles: even blocks hist, odd blocks gemm1.
// hist: u32 packed atomic (count in [26:31], ew 10.16 fixed in [0:25]);
// bins padded to 16B stride; old>>26 = this edge's rank at its destination.
__global__ __launch_bounds__(256) void gemm1_hist_kernel(
    const float* __restrict__ A, const float* __restrict__ W,
    uint* __restrict__ Y, int n, int nstrip, int MBg,
    const int* __restrict__ col, const float* __restrict__ ew,
    uint* __restrict__ dc32, unsigned char* __restrict__ rank, int E, int HB) {
  __shared__ __align__(16) char smem[49152];
  int bid = blockIdx.x;
  if (bid & 1) {
    gemm_body<float>(A, W, Y, n, nstrip, threadIdx.x, bid >> 1, MBg, smem);
    return;
  }
  int stride = HB * 256;
  for (int e = (bid >> 1) * 256 + threadIdx.x; e < E; e += 4 * stride) {
#pragma unroll
    for (int q = 0; q < 4; ++q) {
      int eq = e + q * stride;
      if (eq < E) {
        int c = col[eq];
        uint pack = (1u << 26) + __float2uint_rn(ew[eq] * 65536.0f);
        uint old = atomicAdd(&dc32[(size_t)c * 4], pack);
        rank[eq] = (unsigned char)(old >> 26);
      }
    }
  }
}

// standalone gemm for layer 2 (fp16 A)
__global__ __launch_bounds__(256) void gemm_mfma_kernel(
    const _Float16* __restrict__ A, const float* __restrict__ W,
    uint* __restrict__ Y, int n, int nstrip) {
  __shared__ __align__(16) char smem[49152];
  gemm_body<_Float16>(A, W, Y, n, nstrip, threadIdx.x, blockIdx.x, gridDim.x, smem);
}

// K2: fused node unpack (dis, graph starts) + per-block scan of counts
__global__ __launch_bounds__(256) void node_scan_kernel(
    const uint* __restrict__ dc32, float* __restrict__ dis,
    const int* __restrict__ batch, int* __restrict__ start,
    int* __restrict__ off, int* __restrict__ part, int n, int G) {
  __shared__ int tmp[256];
  int tid = threadIdx.x;
  int i = blockIdx.x * 256 + tid;
  int v = 0;
  if (i < n) {
    uint p = dc32[(size_t)i * 4];
    v = (int)(p >> 26);
    float deg = (float)(p & 0x3FFFFFFu) * (1.0f / 65536.0f);
    dis[i] = rsqrtf(deg + 1.0f);
    int b = batch[i];
    if (i == 0) {
      for (int h = 0; h <= b; ++h) start[h] = 0;
    } else {
      int bp = batch[i - 1];
      for (int h = bp + 1; h <= b; ++h) start[h] = i;
    }
    if (i == n - 1) {
      for (int h = b + 1; h <= G; ++h) start[h] = n;
    }
  }
  tmp[tid] = v;
  __syncthreads();
  for (int d = 1; d < 256; d <<= 1) {
    int t = (tid >= d) ? tmp[tid - d] : 0;
    __syncthreads();
    tmp[tid] += t;
    __syncthreads();
  }
  if (i < n) off[i] = tmp[tid] - v;       // exclusive
  if (tid == 255) part[blockIdx.x] = tmp[255];
}

// K3b: scan the block sums (single block, nb <= 512)
__global__ __launch_bounds__(512) void scan_part_kernel(int* part, int nb) {
  __shared__ int tmp[512];
  int tid = threadIdx.x;
  int v = (tid < nb) ? part[tid] : 0;
  tmp[tid] = v;
  __syncthreads();
  for (int d = 1; d < 512; d <<= 1) {
    int t = (tid >= d) ? tmp[tid - d] : 0;
    __syncthreads();
    tmp[tid] += t;
    __syncthreads();
  }
  if (tid < nb) part[tid] = tmp[tid] - v; // exclusive
}

// K3c: add block offsets; write sentinel off[n] = E
__global__ __launch_bounds__(256) void scan_add_kernel(
    int* __restrict__ off, const int* __restrict__ part, int n, int total) {
  int i = blockIdx.x * 256 + threadIdx.x;
  if (i < n) off[i] += part[blockIdx.x];
  if (i == 0) off[n] = total;
}

// K4: atomic-free CSR fill; entry = row<<15 | q15(dis[row]*ew)
__global__ __launch_bounds__(256) void fill_kernel(
    const int* __restrict__ row, const int* __restrict__ col,
    const float* __restrict__ ew, const unsigned char* __restrict__ rank,
    const float* __restrict__ dis, const int* __restrict__ off,
    uint* __restrict__ csr, int E) {
  int e = blockIdx.x * 256 + threadIdx.x;
  if (e < E) {
    int c = col[e];
    int r = row[e];
    int slot = off[c] + (int)rank[e];
    uint nq = __float2uint_rn(dis[r] * ew[e] * 32768.0f);
    nq = min(nq, 32767u);
    csr[slot] = ((uint)r << 15) | nq;
  }
}

// Aggregate (pull), dual-edge half-wave: lane = (par:1)(hl:5); lane loads
// uint2 = 4 fp16 features of edge (i+par)'s source row; 32 lanes cover the
// 256B row, wave gathers 2 rows/instruction. Parities combined via shfl_xor.
// out = relu( dc*( sum_e nrm_e*xw[src_e] + dc*xw_self ) + bias ), fp16 out.
__global__ __launch_bounds__(256) void agg_kernel(
    const uint* __restrict__ xw, const uint* __restrict__ csr,
    const float* __restrict__ dis, const int* __restrict__ off,
    const float* __restrict__ bias, uint* __restrict__ out, int n) {
  int node = blockIdx.x * 4 + (threadIdx.x >> 6);
  if (node >= n) return;
  int lane = threadIdx.x & 63;
  int hl = lane & 31;          // feature group: features 4*hl .. 4*hl+3
  int par = lane >> 5;         // edge parity
  const uint2* xw2 = (const uint2*)xw;
  float dc = dis[node];
  float a0, a1, a2, a3;
  {
    uint2 v = xw2[((size_t)node << 5) + hl];
    float2 lo = __half22float2(*(const __half2*)&v.x);
    float2 hi = __half22float2(*(const __half2*)&v.y);
    float sd = (par == 0) ? dc : 0.0f;   // self term counted once
    a0 = sd * lo.x; a1 = sd * lo.y; a2 = sd * hi.x; a3 = sd * hi.y;
  }
  const float qs = 1.0f / 32768.0f;
  int s = off[node], t = off[node + 1];
  int i = s;
  for (; i + 8 <= t; i += 8) {           // 4 edges per lane-parity
    uint e0 = csr[i + par];
    uint e1 = csr[i + 2 + par];
    uint e2 = csr[i + 4 + par];
    uint e3 = csr[i + 6 + par];
    uint2 v0 = xw2[((size_t)(e0 >> 15) << 5) + hl];
    uint2 v1 = xw2[((size_t)(e1 >> 15) << 5) + hl];
    uint2 v2 = xw2[((size_t)(e2 >> 15) << 5) + hl];
    uint2 v3 = xw2[((size_t)(e3 >> 15) << 5) + hl];
    float n0 = (float)(e0 & 0x7FFFu) * qs;
    float n1 = (float)(e1 & 0x7FFFu) * qs;
    float n2 = (float)(e2 & 0x7FFFu) * qs;
    float n3 = (float)(e3 & 0x7FFFu) * qs;
    float2 l0 = __half22float2(*(const __half2*)&v0.x);
    float2 h0 = __half22float2(*(const __half2*)&v0.y);
    float2 l1 = __half22float2(*(const __half2*)&v1.x);
    float2 h1 = __half22float2(*(const __half2*)&v1.y);
    float2 l2 = __half22float2(*(const __half2*)&v2.x);
    float2 h2 = __half22float2(*(const __half2*)&v2.y);
    float2 l3 = __half22float2(*(const __half2*)&v3.x);
    float2 h3 = __half22float2(*(const __half2*)&v3.y);
    a0 += n0 * l0.x; a1 += n0 * l0.y; a2 += n0 * h0.x; a3 += n0 * h0.y;
    a0 += n1 * l1.x; a1 += n1 * l1.y; a2 += n1 * h1.x; a3 += n1 * h1.y;
    a0 += n2 * l2.x; a1 += n2 * l2.y; a2 += n2 * h2.x; a3 += n2 * h2.y;
    a0 += n3 * l3.x; a1 += n3 * l3.y; a2 += n3 * h3.x; a3 += n3 * h3.y;
  }
  for (; i < t; i += 2) {                // tail: up to 1 edge per parity
    if (i + par < t) {
      uint e = csr[i + par];
      uint2 v = xw2[((size_t)(e >> 15) << 5) + hl];
      float nn = (float)(e & 0x7FFFu) * qs;
      float2 lo = __half22float2(*(const __half2*)&v.x);
      float2 hi = __half22float2(*(const __half2*)&v.y);
      a0 += nn * lo.x; a1 += nn * lo.y; a2 += nn * hi.x; a3 += nn * hi.y;
    }
  }
  a0 += __shfl_xor(a0, 32);
  a1 += __shfl_xor(a1, 32);
  a2 += __shfl_xor(a2, 32);
  a3 += __shfl_xor(a3, 32);
  if (par == 0) {
    float4 b = *(const float4*)(bias + hl * 4);
    a0 = fmaxf(dc * a0 + b.x, 0.0f);
    a1 = fmaxf(dc * a1 + b.y, 0.0f);
    a2 = fmaxf(dc * a2 + b.z, 0.0f);
    a3 = fmaxf(dc * a3 + b.w, 0.0f);
    __half2 p0 = __floats2half2_rn(a0, a1);
    __half2 p1 = __floats2half2_rn(a2, a3);
    ((uint2*)out)[((size_t)node << 5) + hl] = make_uint2(*(uint*)&p0, *(uint*)&p1);
  }
}

// Mean-pool over sorted batch segments: 256 threads, 4 row-groups + LDS reduce.
__global__ __launch_bounds__(256) void pool_kernel(
    const uint* __restrict__ h, const int* __restrict__ start,
    float* __restrict__ pooled) {
  __shared__ float2 red[256];
  int g = blockIdx.x;
  int grp = threadIdx.x >> 6, f = threadIdx.x & 63;
  int s = start[g], e = start[g + 1];
  float s0 = 0.0f, s1 = 0.0f;
  for (int r = s + grp; r < e; r += 4) {
    uint v = h[((size_t)r << 6) + f];
    float2 fv = __half22float2(*(const __half2*)&v);
    s0 += fv.x;
    s1 += fv.y;
  }
  red[threadIdx.x] = make_float2(s0, s1);
  __syncthreads();
  if (grp == 0) {
    float2 a = red[f], b = red[64 + f], c = red[128 + f], d = red[192 + f];
    float inv = 1.0f / (float)max(e - s, 1);
    pooled[g * HDIM + 2 * f]     = (a.x + b.x + c.x + d.x) * inv;
    pooled[g * HDIM + 2 * f + 1] = (a.y + b.y + c.y + d.y) * inv;
  }
}

// Final: out[g][o] = dot(pooled[g], Wl[:,o]) + bl[o]
__global__ __launch_bounds__(64) void final_kernel(
    const float* __restrict__ pooled, const float* __restrict__ Wl,
    const float* __restrict__ bl, float* __restrict__ out) {
  int g = blockIdx.x;
  int lane = threadIdx.x;
  float p0 = pooled[g * HDIM + lane];
  float p1 = pooled[g * HDIM + 64 + lane];
#pragma unroll
  for (int o = 0; o < 2; ++o) {
    float s = p0 * Wl[lane * 2 + o] + p1 * Wl[(64 + lane) * 2 + o];
    for (int d = 32; d > 0; d >>= 1) s += __shfl_down(s, d);
    if (lane == 0) out[g * 2 + o] = s + bl[o];
  }
}

extern "C" void kernel_launch(void* const* d_in, const int* in_sizes, int n_in,
                              void* d_out, int out_size, void* d_ws, size_t ws_size,
                              hipStream_t stream) {
  const float* x     = (const float*)d_in[0];
  const int*   ei    = (const int*)d_in[1];
  const float* ew    = (const float*)d_in[2];
  const int*   batch = (const int*)d_in[3];
  const float* W1    = (const float*)d_in[4];
  const float* b1    = (const float*)d_in[5];
  const float* W2    = (const float*)d_in[6];
  const float* b2    = (const float*)d_in[7];
  const float* Wl    = (const float*)d_in[8];
  const float* bl    = (const float*)d_in[9];
  float* out = (float*)d_out;

  const int N = in_sizes[0] / HDIM;     // 100000
  const int E = in_sizes[2];            // 1600000
  const int G = out_size / 2;           // 512

  const int* row = ei;
  const int* col = ei + E;

  // ---- workspace layout (256B aligned) ----
  auto al = [](size_t v) { return (v + 255) & ~(size_t)255; };
  char* ws = (char*)d_ws;
  size_t o_dc32   = 0;                                   // u32[N] @16B stride (zeroed)
  size_t zero_end = o_dc32   + al((size_t)N * 16);
  size_t o_rank   = zero_end;                            // u8[E]
  size_t o_dis    = o_rank   + al((size_t)E);            // f32[N]
  size_t o_start  = o_dis    + al((size_t)N * 4);        // i32[G+1]
  size_t o_off    = o_start  + al(((size_t)G + 1) * 4);  // i32[N+1]
  size_t o_part   = o_off    + al(((size_t)N + 1) * 4);  // i32[512]
  size_t o_csr    = o_part   + al(2048);                 // u32[E]
  size_t o_xw     = o_csr    + al((size_t)E * 4);        // fp16x2 uint[N*64]
  size_t o_h      = o_xw     + al((size_t)N * 64 * 4);   // fp16x2 uint[N*64]
  size_t o_pooled = o_h      + al((size_t)N * 64 * 4);   // f32[G*128]

  uint*  dc32    = (uint*) (ws + o_dc32);
  unsigned char* rank = (unsigned char*)(ws + o_rank);
  float* dis     = (float*)(ws + o_dis);
  int*   start   = (int*)  (ws + o_start);
  int*   off     = (int*)  (ws + o_off);
  int*   part    = (int*)  (ws + o_part);
  uint*  csr     = (uint*) (ws + o_csr);
  uint*  xw      = (uint*) (ws + o_xw);
  uint*  hbuf    = (uint*) (ws + o_h);
  float* pooled  = (float*)(ws + o_pooled);

  hipMemsetAsync(ws, 0, zero_end, stream);

  int EB = (E + 255) / 256;
  int NB = (N + 255) / 256;
  int nstrip = (N + 15) / 16;
  int MBg = 1024;             // gemm blocks in fused kernel (odd bids)
  int HB  = 1024;             // hist blocks (even bids, 4-deep atomic ILP)
  int MB  = 1024;             // gemm2 blocks
  int AB  = (N + 3) / 4;      // agg blocks (4 waves/block)

  // hist (atomic-bound) || gemm1 (MFMA/BW-bound), roles interleaved by parity
  gemm1_hist_kernel<<<MBg + HB, 256, 0, stream>>>(
      x, W1, xw, N, nstrip, MBg, col, ew, dc32, rank, E, HB);

  node_scan_kernel<<<NB, 256, 0, stream>>>(dc32, dis, batch, start, off, part, N, G);
  scan_part_kernel<<<1, 512, 0, stream>>>(part, NB);
  scan_add_kernel<<<NB, 256, 0, stream>>>(off, part, N, E);

  fill_kernel<<<EB, 256, 0, stream>>>(row, col, ew, rank, dis, off, csr, E);

  // layer 1 aggregate
  agg_kernel<<<AB, 256, 0, stream>>>(xw, csr, dis, off, b1, hbuf, N);

  // layer 2: xw2 = fp16(h1 @ W2) ; h2 = fp16(relu(agg(xw2) + b2))
  gemm_mfma_kernel<<<MB, 256, 0, stream>>>((const _Float16*)hbuf, W2, xw, N, nstrip);
  agg_kernel<<<AB, 256, 0, stream>>>(xw, csr, dis, off, b2, hbuf, N);

  // mean-pool per sorted-batch segment, then linear head
  pool_kernel<<<G, 256, 0, stream>>>(hbuf, start, pooled);
  final_kernel<<<G, 64, 0, stream>>>(pooled, Wl, bl, out);
}

// Round 10
// 247.084 us; speedup vs baseline: 3.9303x; 1.1235x over previous
//
#include <hip/hip_runtime.h>
#include <hip/hip_fp16.h>

// ---------------------------------------------------------------------------
// GCN graph classifier: 2x GCNConv(128->128) + global_mean_pool + Linear(128->2)
// R10: message tables (xw) stored as fp8 e4m3 via HW cvt_pk (encode in gemm
// epilogue, decode in agg) -> halves the E x row gather traffic that bounds
// agg. h (layer activations) stay fp16. Fused gemm1||hist parity-interleaved,
// u32 packed atomic hist (op-rate wall ~23 Gops/s, proven R9), atomic-free
// fill with q15-packed CSR, sorted-batch pooling.
// ---------------------------------------------------------------------------

#define HDIM 128
typedef unsigned int uint;
typedef _Float16 half8 __attribute__((ext_vector_type(8)));
typedef float f32x4 __attribute__((ext_vector_type(4)));
typedef float f32x2 __attribute__((ext_vector_type(2)));

// ---- gemm body: Y[n][128](fp8 e4m3) = A[n][128] @ W[128][128](f32) ----
// Swapped operands: D = Wt * X^T per 16-row strip (layouts validated R4/R7).
// smem: [0,32768) swizzled fp16 W^T; [32768 + wave*2048) epilogue staging.
template <typename AT>
__device__ __forceinline__ void gemm_body(
    const AT* __restrict__ A, const float* __restrict__ W,
    unsigned char* __restrict__ Y, int n, int nstrip, int tid, int bid,
    int nblk, char* smem) {
  char* Wt = smem;
  for (int t = tid; t < 2048; t += 256) {
    int c = t & 127;
    int k8 = t >> 7;
    const float* wp = W + (size_t)(k8 * 8) * HDIM + c;
    half8 hv;
#pragma unroll
    for (int m = 0; m < 8; ++m) hv[m] = (_Float16)wp[m * HDIM];
    int byte = c * 256 + k8 * 16;
    byte ^= ((c & 7) << 4);
    *(half8*)&Wt[byte] = hv;
  }
  __syncthreads();

  int wave = tid >> 6, lane = tid & 63;
  int l15 = lane & 15, l4 = lane >> 4;
  char* ep = smem + 32768 + wave * 2048;
  int stride = nblk * 4;
  for (int s = bid * 4 + wave; s < nstrip; s += stride) {
    int row0 = s << 4;
    int xrl = min(row0 + l15, n - 1);
    half8 bf[4];
    if constexpr (sizeof(AT) == 4) {
      const float* ap = (const float*)A + (size_t)xrl * HDIM + l4 * 8;
#pragma unroll
      for (int kk = 0; kk < 4; ++kk) {
        float4 u = *(const float4*)(ap + kk * 32);
        float4 v = *(const float4*)(ap + kk * 32 + 4);
        half8 h;
        h[0] = (_Float16)u.x; h[1] = (_Float16)u.y;
        h[2] = (_Float16)u.z; h[3] = (_Float16)u.w;
        h[4] = (_Float16)v.x; h[5] = (_Float16)v.y;
        h[6] = (_Float16)v.z; h[7] = (_Float16)v.w;
        bf[kk] = h;
      }
    } else {
      const half8* ap = (const half8*)((const _Float16*)A + (size_t)xrl * HDIM + l4 * 8);
#pragma unroll
      for (int kk = 0; kk < 4; ++kk) bf[kk] = ap[kk * 4];
    }
    f32x4 acc[8];
#pragma unroll
    for (int cf = 0; cf < 8; ++cf) acc[cf] = (f32x4){0.f, 0.f, 0.f, 0.f};
#pragma unroll
    for (int kk = 0; kk < 4; ++kk) {
#pragma unroll
      for (int cf = 0; cf < 8; ++cf) {
        int c = cf * 16 + l15;
        int byte = c * 256 + kk * 64 + l4 * 16;
        byte ^= ((c & 7) << 4);
        half8 af = *(half8*)&Wt[byte];
        acc[cf] = __builtin_amdgcn_mfma_f32_16x16x32_f16(af, bf[kk], acc[cf], 0, 0, 0);
      }
    }
    // epilogue: pack 4 f32 -> 4 fp8 per cf, stage 16 rows x 128B in LDS,
    // 16B-granular XOR swizzle; read back as 2 passes of 1KB coalesced.
#pragma unroll
    for (int cf = 0; cf < 8; ++cf) {
      int w = 0;
      w = __builtin_amdgcn_cvt_pk_fp8_f32(acc[cf][0], acc[cf][1], w, false);
      w = __builtin_amdgcn_cvt_pk_fp8_f32(acc[cf][2], acc[cf][3], w, true);
      int byte = l15 * 128 + ((cf * 16) ^ ((l15 & 7) << 4)) + l4 * 4;
      *(int*)&ep[byte] = w;
    }
    asm volatile("s_waitcnt lgkmcnt(0)" ::: "memory");
#pragma unroll
    for (int p = 0; p < 2; ++p) {
      int rl = p * 8 + (lane >> 3);          // 0..15
      int c16 = (lane & 7) * 16;
      int byte = rl * 128 + (c16 ^ ((rl & 7) << 4));
      uint4 v = *(uint4*)&ep[byte];
      int orow = row0 + rl;
      if (orow < n)
        *(uint4*)(Y + (size_t)orow * 128 + c16) = v;
    }
  }
}

// K1 fused, interleaved roles: even blocks hist, odd blocks gemm1.
// hist: u32 packed atomic (count in [26:31], ew 10.16 fixed in [0:25]);
// bins padded to 16B stride; old>>26 = this edge's rank at its destination.
__global__ __launch_bounds__(256) void gemm1_hist_kernel(
    const float* __restrict__ A, const float* __restrict__ W,
    unsigned char* __restrict__ Y, int n, int nstrip, int MBg,
    const int* __restrict__ col, const float* __restrict__ ew,
    uint* __restrict__ dc32, unsigned char* __restrict__ rank, int E, int HB) {
  __shared__ __align__(16) char smem[40960];
  int bid = blockIdx.x;
  if (bid & 1) {
    gemm_body<float>(A, W, Y, n, nstrip, threadIdx.x, bid >> 1, MBg, smem);
    return;
  }
  int stride = HB * 256;
  for (int e = (bid >> 1) * 256 + threadIdx.x; e < E; e += 4 * stride) {
#pragma unroll
    for (int q = 0; q < 4; ++q) {
      int eq = e + q * stride;
      if (eq < E) {
        int c = col[eq];
        uint pack = (1u << 26) + __float2uint_rn(ew[eq] * 65536.0f);
        uint old = atomicAdd(&dc32[(size_t)c * 4], pack);
        rank[eq] = (unsigned char)(old >> 26);
      }
    }
  }
}

// standalone gemm for layer 2 (fp16 A)
__global__ __launch_bounds__(256) void gemm_mfma_kernel(
    const _Float16* __restrict__ A, const float* __restrict__ W,
    unsigned char* __restrict__ Y, int n, int nstrip) {
  __shared__ __align__(16) char smem[40960];
  gemm_body<_Float16>(A, W, Y, n, nstrip, threadIdx.x, blockIdx.x, gridDim.x, smem);
}

// K2: fused node unpack (dis, graph starts) + per-block scan of counts
__global__ __launch_bounds__(256) void node_scan_kernel(
    const uint* __restrict__ dc32, float* __restrict__ dis,
    const int* __restrict__ batch, int* __restrict__ start,
    int* __restrict__ off, int* __restrict__ part, int n, int G) {
  __shared__ int tmp[256];
  int tid = threadIdx.x;
  int i = blockIdx.x * 256 + tid;
  int v = 0;
  if (i < n) {
    uint p = dc32[(size_t)i * 4];
    v = (int)(p >> 26);
    float deg = (float)(p & 0x3FFFFFFu) * (1.0f / 65536.0f);
    dis[i] = rsqrtf(deg + 1.0f);
    int b = batch[i];
    if (i == 0) {
      for (int h = 0; h <= b; ++h) start[h] = 0;
    } else {
      int bp = batch[i - 1];
      for (int h = bp + 1; h <= b; ++h) start[h] = i;
    }
    if (i == n - 1) {
      for (int h = b + 1; h <= G; ++h) start[h] = n;
    }
  }
  tmp[tid] = v;
  __syncthreads();
  for (int d = 1; d < 256; d <<= 1) {
    int t = (tid >= d) ? tmp[tid - d] : 0;
    __syncthreads();
    tmp[tid] += t;
    __syncthreads();
  }
  if (i < n) off[i] = tmp[tid] - v;       // exclusive
  if (tid == 255) part[blockIdx.x] = tmp[255];
}

// K3b: scan the block sums (single block, nb <= 512)
__global__ __launch_bounds__(512) void scan_part_kernel(int* part, int nb) {
  __shared__ int tmp[512];
  int tid = threadIdx.x;
  int v = (tid < nb) ? part[tid] : 0;
  tmp[tid] = v;
  __syncthreads();
  for (int d = 1; d < 512; d <<= 1) {
    int t = (tid >= d) ? tmp[tid - d] : 0;
    __syncthreads();
    tmp[tid] += t;
    __syncthreads();
  }
  if (tid < nb) part[tid] = tmp[tid] - v; // exclusive
}

// K3c: add block offsets; write sentinel off[n] = E
__global__ __launch_bounds__(256) void scan_add_kernel(
    int* __restrict__ off, const int* __restrict__ part, int n, int total) {
  int i = blockIdx.x * 256 + threadIdx.x;
  if (i < n) off[i] += part[blockIdx.x];
  if (i == 0) off[n] = total;
}

// K4: atomic-free CSR fill; entry = row<<15 | q15(dis[row]*ew)
__global__ __launch_bounds__(256) void fill_kernel(
    const int* __restrict__ row, const int* __restrict__ col,
    const float* __restrict__ ew, const unsigned char* __restrict__ rank,
    const float* __restrict__ dis, const int* __restrict__ off,
    uint* __restrict__ csr, int E) {
  int e = blockIdx.x * 256 + threadIdx.x;
  if (e < E) {
    int c = col[e];
    int r = row[e];
    int slot = off[c] + (int)rank[e];
    uint nq = __float2uint_rn(dis[r] * ew[e] * 32768.0f);
    nq = min(nq, 32767u);
    csr[slot] = ((uint)r << 15) | nq;
  }
}

// Aggregate (pull), dual-edge half-wave, fp8 table: lane = (par:1)(hl:5);
// lane loads uint = 4 fp8 features of edge (i+par)'s source row; 32 lanes
// cover the 128B row; wave gathers 2 rows/instruction; parity combine via
// shfl_xor. out = relu( dc*( sum_e nrm_e*xw[src_e] + dc*xw_self ) + b ), fp16.
__global__ __launch_bounds__(256) void agg_kernel(
    const uint* __restrict__ xw, const uint* __restrict__ csr,
    const float* __restrict__ dis, const int* __restrict__ off,
    const float* __restrict__ bias, uint* __restrict__ out, int n) {
  int node = blockIdx.x * 4 + (threadIdx.x >> 6);
  if (node >= n) return;
  int lane = threadIdx.x & 63;
  int hl = lane & 31;          // feature group: features 4*hl .. 4*hl+3
  int par = lane >> 5;         // edge parity
  float dc = dis[node];
  float a0, a1, a2, a3;
  {
    uint v = xw[(size_t)node * 32 + hl];
    f32x2 lo = __builtin_amdgcn_cvt_pk_f32_fp8((int)v, false);
    f32x2 hi = __builtin_amdgcn_cvt_pk_f32_fp8((int)v, true);
    float sd = (par == 0) ? dc : 0.0f;   // self term counted once
    a0 = sd * lo[0]; a1 = sd * lo[1]; a2 = sd * hi[0]; a3 = sd * hi[1];
  }
  const float qs = 1.0f / 32768.0f;
  int s = off[node], t = off[node + 1];
  int i = s;
  for (; i + 8 <= t; i += 8) {           // 4 edges per lane-parity
    uint e0 = csr[i + par];
    uint e1 = csr[i + 2 + par];
    uint e2 = csr[i + 4 + par];
    uint e3 = csr[i + 6 + par];
    uint v0 = xw[(size_t)(e0 >> 15) * 32 + hl];
    uint v1 = xw[(size_t)(e1 >> 15) * 32 + hl];
    uint v2 = xw[(size_t)(e2 >> 15) * 32 + hl];
    uint v3 = xw[(size_t)(e3 >> 15) * 32 + hl];
    float n0 = (float)(e0 & 0x7FFFu) * qs;
    float n1 = (float)(e1 & 0x7FFFu) * qs;
    float n2 = (float)(e2 & 0x7FFFu) * qs;
    float n3 = (float)(e3 & 0x7FFFu) * qs;
    f32x2 l0 = __builtin_amdgcn_cvt_pk_f32_fp8((int)v0, false);
    f32x2 h0 = __builtin_amdgcn_cvt_pk_f32_fp8((int)v0, true);
    f32x2 l1 = __builtin_amdgcn_cvt_pk_f32_fp8((int)v1, false);
    f32x2 h1 = __builtin_amdgcn_cvt_pk_f32_fp8((int)v1, true);
    f32x2 l2 = __builtin_amdgcn_cvt_pk_f32_fp8((int)v2, false);
    f32x2 h2 = __builtin_amdgcn_cvt_pk_f32_fp8((int)v2, true);
    f32x2 l3 = __builtin_amdgcn_cvt_pk_f32_fp8((int)v3, false);
    f32x2 h3 = __builtin_amdgcn_cvt_pk_f32_fp8((int)v3, true);
    a0 += n0 * l0[0]; a1 += n0 * l0[1]; a2 += n0 * h0[0]; a3 += n0 * h0[1];
    a0 += n1 * l1[0]; a1 += n1 * l1[1]; a2 += n1 * h1[0]; a3 += n1 * h1[1];
    a0 += n2 * l2[0]; a1 += n2 * l2[1]; a2 += n2 * h2[0]; a3 += n2 * h2[1];
    a0 += n3 * l3[0]; a1 += n3 * l3[1]; a2 += n3 * h3[0]; a3 += n3 * h3[1];
  }
  for (; i < t; i += 2) {                // tail: up to 1 edge per parity
    if (i + par < t) {
      uint e = csr[i + par];
      uint v = xw[(size_t)(e >> 15) * 32 + hl];
      float nn = (float)(e & 0x7FFFu) * qs;
      f32x2 lo = __builtin_amdgcn_cvt_pk_f32_fp8((int)v, false);
      f32x2 hi = __builtin_amdgcn_cvt_pk_f32_fp8((int)v, true);
      a0 += nn * lo[0]; a1 += nn * lo[1]; a2 += nn * hi[0]; a3 += nn * hi[1];
    }
  }
  a0 += __shfl_xor(a0, 32);
  a1 += __shfl_xor(a1, 32);
  a2 += __shfl_xor(a2, 32);
  a3 += __shfl_xor(a3, 32);
  if (par == 0) {
    float4 b = *(const float4*)(bias + hl * 4);
    a0 = fmaxf(dc * a0 + b.x, 0.0f);
    a1 = fmaxf(dc * a1 + b.y, 0.0f);
    a2 = fmaxf(dc * a2 + b.z, 0.0f);
    a3 = fmaxf(dc * a3 + b.w, 0.0f);
    __half2 p0 = __floats2half2_rn(a0, a1);
    __half2 p1 = __floats2half2_rn(a2, a3);
    ((uint2*)out)[(size_t)node * 32 + hl] = make_uint2(*(uint*)&p0, *(uint*)&p1);
  }
}

// Mean-pool over sorted batch segments: 256 threads, 4 row-groups + LDS reduce.
__global__ __launch_bounds__(256) void pool_kernel(
    const uint* __restrict__ h, const int* __restrict__ start,
    float* __restrict__ pooled) {
  __shared__ float2 red[256];
  int g = blockIdx.x;
  int grp = threadIdx.x >> 6, f = threadIdx.x & 63;
  int s = start[g], e = start[g + 1];
  float s0 = 0.0f, s1 = 0.0f;
  for (int r = s + grp; r < e; r += 4) {
    uint v = h[((size_t)r << 6) + f];
    float2 fv = __half22float2(*(const __half2*)&v);
    s0 += fv.x;
    s1 += fv.y;
  }
  red[threadIdx.x] = make_float2(s0, s1);
  __syncthreads();
  if (grp == 0) {
    float2 a = red[f], b = red[64 + f], c = red[128 + f], d = red[192 + f];
    float inv = 1.0f / (float)max(e - s, 1);
    pooled[g * HDIM + 2 * f]     = (a.x + b.x + c.x + d.x) * inv;
    pooled[g * HDIM + 2 * f + 1] = (a.y + b.y + c.y + d.y) * inv;
  }
}

// Final: out[g][o] = dot(pooled[g], Wl[:,o]) + bl[o]
__global__ __launch_bounds__(64) void final_kernel(
    const float* __restrict__ pooled, const float* __restrict__ Wl,
    const float* __restrict__ bl, float* __restrict__ out) {
  int g = blockIdx.x;
  int lane = threadIdx.x;
  float p0 = pooled[g * HDIM + lane];
  float p1 = pooled[g * HDIM + 64 + lane];
#pragma unroll
  for (int o = 0; o < 2; ++o) {
    float s = p0 * Wl[lane * 2 + o] + p1 * Wl[(64 + lane) * 2 + o];
    for (int d = 32; d > 0; d >>= 1) s += __shfl_down(s, d);
    if (lane == 0) out[g * 2 + o] = s + bl[o];
  }
}

extern "C" void kernel_launch(void* const* d_in, const int* in_sizes, int n_in,
                              void* d_out, int out_size, void* d_ws, size_t ws_size,
                              hipStream_t stream) {
  const float* x     = (const float*)d_in[0];
  const int*   ei    = (const int*)d_in[1];
  const float* ew    = (const float*)d_in[2];
  const int*   batch = (const int*)d_in[3];
  const float* W1    = (const float*)d_in[4];
  const float* b1    = (const float*)d_in[5];
  const float* W2    = (const float*)d_in[6];
  const float* b2    = (const float*)d_in[7];
  const float* Wl    = (const float*)d_in[8];
  const float* bl    = (const float*)d_in[9];
  float* out = (float*)d_out;

  const int N = in_sizes[0] / HDIM;     // 100000
  const int E = in_sizes[2];            // 1600000
  const int G = out_size / 2;           // 512

  const int* row = ei;
  const int* col = ei + E;

  // ---- workspace layout (256B aligned) ----
  auto al = [](size_t v) { return (v + 255) & ~(size_t)255; };
  char* ws = (char*)d_ws;
  size_t o_dc32   = 0;                                   // u32[N] @16B stride (zeroed)
  size_t zero_end = o_dc32   + al((size_t)N * 16);
  size_t o_rank   = zero_end;                            // u8[E]
  size_t o_dis    = o_rank   + al((size_t)E);            // f32[N]
  size_t o_start  = o_dis    + al((size_t)N * 4);        // i32[G+1]
  size_t o_off    = o_start  + al(((size_t)G + 1) * 4);  // i32[N+1]
  size_t o_part   = o_off    + al(((size_t)N + 1) * 4);  // i32[512]
  size_t o_csr    = o_part   + al(2048);                 // u32[E]
  size_t o_xw     = o_csr    + al((size_t)E * 4);        // fp8 u8[N*128]
  size_t o_h      = o_xw     + al((size_t)N * 128);      // fp16x2 uint[N*64]
  size_t o_pooled = o_h      + al((size_t)N * 64 * 4);   // f32[G*128]

  uint*  dc32    = (uint*) (ws + o_dc32);
  unsigned char* rank = (unsigned char*)(ws + o_rank);
  float* dis     = (float*)(ws + o_dis);
  int*   start   = (int*)  (ws + o_start);
  int*   off     = (int*)  (ws + o_off);
  int*   part    = (int*)  (ws + o_part);
  uint*  csr     = (uint*) (ws + o_csr);
  unsigned char* xw = (unsigned char*)(ws + o_xw);
  uint*  hbuf    = (uint*) (ws + o_h);
  float* pooled  = (float*)(ws + o_pooled);

  hipMemsetAsync(ws, 0, zero_end, stream);

  int EB = (E + 255) / 256;
  int NB = (N + 255) / 256;
  int nstrip = (N + 15) / 16;
  int MBg = 1024;             // gemm blocks in fused kernel (odd bids)
  int HB  = 1024;             // hist blocks (even bids, 4-deep atomic ILP)
  int MB  = 1024;             // gemm2 blocks
  int AB  = (N + 3) / 4;      // agg blocks (4 waves/block)

  // hist (atomic-bound) || gemm1 (MFMA/BW-bound), roles interleaved by parity
  gemm1_hist_kernel<<<MBg + HB, 256, 0, stream>>>(
      x, W1, xw, N, nstrip, MBg, col, ew, dc32, rank, E, HB);

  node_scan_kernel<<<NB, 256, 0, stream>>>(dc32, dis, batch, start, off, part, N, G);
  scan_part_kernel<<<1, 512, 0, stream>>>(part, NB);
  scan_add_kernel<<<NB, 256, 0, stream>>>(off, part, N, E);

  fill_kernel<<<EB, 256, 0, stream>>>(row, col, ew, rank, dis, off, csr, E);

  // layer 1 aggregate (fp8 gather -> fp16 h1)
  agg_kernel<<<AB, 256, 0, stream>>>((const uint*)xw, csr, dis, off, b1, hbuf, N);

  // layer 2: xw2 = fp8(h1 @ W2) ; h2 = fp16(relu(agg(xw2) + b2))
  gemm_mfma_kernel<<<MB, 256, 0, stream>>>((const _Float16*)hbuf, W2, xw, N, nstrip);
  agg_kernel<<<AB, 256, 0, stream>>>((const uint*)xw, csr, dis, off, b2, hbuf, N);

  // mean-pool per sorted-batch segment, then linear head
  pool_kernel<<<G, 256, 0, stream>>>(hbuf, start, pooled);
  final_kernel<<<G, 64, 0, stream>>>(pooled, Wl, bl, out);
}

// Round 11
// 245.871 us; speedup vs baseline: 3.9497x; 1.0049x over previous
//
#include <hip/hip_runtime.h>
#include <hip/hip_fp16.h>

// ---------------------------------------------------------------------------
// GCN graph classifier: 2x GCNConv(128->128) + global_mean_pool + Linear(128->2)
// R11: decoupled-lookback single-kernel scan (replaces 3 scan kernels);
// pool+final fused; agg gains a 16-wide gather stage. fp8 message tables,
// fused gemm1||hist parity-interleaved, u32 packed atomic hist (rate wall),
// atomic-free fill with q15 CSR.
// ---------------------------------------------------------------------------

#define HDIM 128
typedef unsigned int uint;
typedef unsigned long long u64;
typedef _Float16 half8 __attribute__((ext_vector_type(8)));
typedef float f32x4 __attribute__((ext_vector_type(4)));
typedef float f32x2 __attribute__((ext_vector_type(2)));

// ---- gemm body: Y[n][128](fp8 e4m3) = A[n][128] @ W[128][128](f32) ----
template <typename AT>
__device__ __forceinline__ void gemm_body(
    const AT* __restrict__ A, const float* __restrict__ W,
    unsigned char* __restrict__ Y, int n, int nstrip, int tid, int bid,
    int nblk, char* smem) {
  char* Wt = smem;
  for (int t = tid; t < 2048; t += 256) {
    int c = t & 127;
    int k8 = t >> 7;
    const float* wp = W + (size_t)(k8 * 8) * HDIM + c;
    half8 hv;
#pragma unroll
    for (int m = 0; m < 8; ++m) hv[m] = (_Float16)wp[m * HDIM];
    int byte = c * 256 + k8 * 16;
    byte ^= ((c & 7) << 4);
    *(half8*)&Wt[byte] = hv;
  }
  __syncthreads();

  int wave = tid >> 6, lane = tid & 63;
  int l15 = lane & 15, l4 = lane >> 4;
  char* ep = smem + 32768 + wave * 2048;
  int stride = nblk * 4;
  for (int s = bid * 4 + wave; s < nstrip; s += stride) {
    int row0 = s << 4;
    int xrl = min(row0 + l15, n - 1);
    half8 bf[4];
    if constexpr (sizeof(AT) == 4) {
      const float* ap = (const float*)A + (size_t)xrl * HDIM + l4 * 8;
#pragma unroll
      for (int kk = 0; kk < 4; ++kk) {
        float4 u = *(const float4*)(ap + kk * 32);
        float4 v = *(const float4*)(ap + kk * 32 + 4);
        half8 h;
        h[0] = (_Float16)u.x; h[1] = (_Float16)u.y;
        h[2] = (_Float16)u.z; h[3] = (_Float16)u.w;
        h[4] = (_Float16)v.x; h[5] = (_Float16)v.y;
        h[6] = (_Float16)v.z; h[7] = (_Float16)v.w;
        bf[kk] = h;
      }
    } else {
      const half8* ap = (const half8*)((const _Float16*)A + (size_t)xrl * HDIM + l4 * 8);
#pragma unroll
      for (int kk = 0; kk < 4; ++kk) bf[kk] = ap[kk * 4];
    }
    f32x4 acc[8];
#pragma unroll
    for (int cf = 0; cf < 8; ++cf) acc[cf] = (f32x4){0.f, 0.f, 0.f, 0.f};
#pragma unroll
    for (int kk = 0; kk < 4; ++kk) {
#pragma unroll
      for (int cf = 0; cf < 8; ++cf) {
        int c = cf * 16 + l15;
        int byte = c * 256 + kk * 64 + l4 * 16;
        byte ^= ((c & 7) << 4);
        half8 af = *(half8*)&Wt[byte];
        acc[cf] = __builtin_amdgcn_mfma_f32_16x16x32_f16(af, bf[kk], acc[cf], 0, 0, 0);
      }
    }
    // epilogue: 4 f32 -> 4 fp8 per cf, stage 16x128B in LDS (16B XOR swizzle)
#pragma unroll
    for (int cf = 0; cf < 8; ++cf) {
      int w = 0;
      w = __builtin_amdgcn_cvt_pk_fp8_f32(acc[cf][0], acc[cf][1], w, false);
      w = __builtin_amdgcn_cvt_pk_fp8_f32(acc[cf][2], acc[cf][3], w, true);
      int byte = l15 * 128 + ((cf * 16) ^ ((l15 & 7) << 4)) + l4 * 4;
      *(int*)&ep[byte] = w;
    }
    asm volatile("s_waitcnt lgkmcnt(0)" ::: "memory");
#pragma unroll
    for (int p = 0; p < 2; ++p) {
      int rl = p * 8 + (lane >> 3);          // 0..15
      int c16 = (lane & 7) * 16;
      int byte = rl * 128 + (c16 ^ ((rl & 7) << 4));
      uint4 v = *(uint4*)&ep[byte];
      int orow = row0 + rl;
      if (orow < n)
        *(uint4*)(Y + (size_t)orow * 128 + c16) = v;
    }
  }
}

// K1 fused, interleaved roles: even blocks hist, odd blocks gemm1.
__global__ __launch_bounds__(256) void gemm1_hist_kernel(
    const float* __restrict__ A, const float* __restrict__ W,
    unsigned char* __restrict__ Y, int n, int nstrip, int MBg,
    const int* __restrict__ col, const float* __restrict__ ew,
    uint* __restrict__ dc32, unsigned char* __restrict__ rank, int E, int HB) {
  __shared__ __align__(16) char smem[40960];
  int bid = blockIdx.x;
  if (bid & 1) {
    gemm_body<float>(A, W, Y, n, nstrip, threadIdx.x, bid >> 1, MBg, smem);
    return;
  }
  int stride = HB * 256;
  for (int e = (bid >> 1) * 256 + threadIdx.x; e < E; e += 4 * stride) {
#pragma unroll
    for (int q = 0; q < 4; ++q) {
      int eq = e + q * stride;
      if (eq < E) {
        int c = col[eq];
        uint pack = (1u << 26) + __float2uint_rn(ew[eq] * 65536.0f);
        uint old = atomicAdd(&dc32[(size_t)c * 4], pack);
        rank[eq] = (unsigned char)(old >> 26);
      }
    }
  }
}

// standalone gemm for layer 2 (fp16 A)
__global__ __launch_bounds__(256) void gemm_mfma_kernel(
    const _Float16* __restrict__ A, const float* __restrict__ W,
    unsigned char* __restrict__ Y, int n, int nstrip) {
  __shared__ __align__(16) char smem[40960];
  gemm_body<_Float16>(A, W, Y, n, nstrip, threadIdx.x, blockIdx.x, gridDim.x, smem);
}

// K2: node unpack (dis, graph starts) + FULL exclusive scan of counts via
// decoupled lookback (flag in bits[62:63]: 1=aggregate, 2=inclusive prefix;
// value in low 32). All blocks co-resident (grid=391 << capacity) -> no
// deadlock; single packed u64 atomic word = coherent value+flag handoff.
__global__ __launch_bounds__(256) void node_scan_kernel(
    const uint* __restrict__ dc32, float* __restrict__ dis,
    const int* __restrict__ batch, int* __restrict__ start,
    int* __restrict__ off, u64* __restrict__ desc, int n, int G, int E) {
  __shared__ int tmp[256];
  __shared__ int exs;
  int tid = threadIdx.x;
  int b = blockIdx.x;
  int i = b * 256 + tid;
  int v = 0;
  if (i < n) {
    uint p = dc32[(size_t)i * 4];
    v = (int)(p >> 26);
    float deg = (float)(p & 0x3FFFFFFu) * (1.0f / 65536.0f);
    dis[i] = rsqrtf(deg + 1.0f);
    int bb = batch[i];
    if (i == 0) {
      for (int h = 0; h <= bb; ++h) start[h] = 0;
      off[n] = E;
    } else {
      int bp = batch[i - 1];
      for (int h = bp + 1; h <= bb; ++h) start[h] = i;
    }
    if (i == n - 1) {
      for (int h = bb + 1; h <= G; ++h) start[h] = n;
    }
  }
  tmp[tid] = v;
  __syncthreads();
  for (int d = 1; d < 256; d <<= 1) {
    int t = (tid >= d) ? tmp[tid - d] : 0;
    __syncthreads();
    tmp[tid] += t;
    __syncthreads();
  }
  if (tid == 0) {
    u64 agg = (u64)(uint)tmp[255];
    int ex = 0;
    if (b == 0) {
      atomicExch(&desc[0], (2ull << 62) | agg);
    } else {
      atomicExch(&desc[b], (1ull << 62) | agg);
      int p = b - 1;
      while (true) {
        u64 s = atomicAdd(&desc[p], 0ull);
        u64 fl = s >> 62;
        if (fl == 0) continue;           // not yet published
        ex += (int)(uint)s;
        if (fl == 2) break;              // inclusive prefix reached
        --p;
      }
      atomicExch(&desc[b], (2ull << 62) | (u64)(uint)(ex + tmp[255]));
    }
    exs = ex;
  }
  __syncthreads();
  if (i < n) off[i] = exs + tmp[tid] - v;   // exclusive global prefix
}

// K4: atomic-free CSR fill; entry = row<<15 | q15(dis[row]*ew)
__global__ __launch_bounds__(256) void fill_kernel(
    const int* __restrict__ row, const int* __restrict__ col,
    const float* __restrict__ ew, const unsigned char* __restrict__ rank,
    const float* __restrict__ dis, const int* __restrict__ off,
    uint* __restrict__ csr, int E) {
  int e = blockIdx.x * 256 + threadIdx.x;
  if (e < E) {
    int c = col[e];
    int r = row[e];
    int slot = off[c] + (int)rank[e];
    uint nq = __float2uint_rn(dis[r] * ew[e] * 32768.0f);
    nq = min(nq, 32767u);
    csr[slot] = ((uint)r << 15) | nq;
  }
}

// Aggregate (pull), dual-edge half-wave, fp8 table. 16-wide stage: 8 gathers
// in flight per parity; then 8-wide; scalar-pair tail.
__global__ __launch_bounds__(256) void agg_kernel(
    const uint* __restrict__ xw, const uint* __restrict__ csr,
    const float* __restrict__ dis, const int* __restrict__ off,
    const float* __restrict__ bias, uint* __restrict__ out, int n) {
  int node = blockIdx.x * 4 + (threadIdx.x >> 6);
  if (node >= n) return;
  int lane = threadIdx.x & 63;
  int hl = lane & 31;          // feature group: features 4*hl .. 4*hl+3
  int par = lane >> 5;         // edge parity
  float dc = dis[node];
  float a0, a1, a2, a3;
  {
    uint v = xw[(size_t)node * 32 + hl];
    f32x2 lo = __builtin_amdgcn_cvt_pk_f32_fp8((int)v, false);
    f32x2 hi = __builtin_amdgcn_cvt_pk_f32_fp8((int)v, true);
    float sd = (par == 0) ? dc : 0.0f;   // self term counted once
    a0 = sd * lo[0]; a1 = sd * lo[1]; a2 = sd * hi[0]; a3 = sd * hi[1];
  }
  const float qs = 1.0f / 32768.0f;
  int s = off[node], t = off[node + 1];
  int i = s;
  for (; i + 16 <= t; i += 16) {         // 8 edges per lane-parity
    uint ee[8];
#pragma unroll
    for (int j = 0; j < 8; ++j) ee[j] = csr[i + 2 * j + par];
    uint vv[8];
#pragma unroll
    for (int j = 0; j < 8; ++j) vv[j] = xw[(size_t)(ee[j] >> 15) * 32 + hl];
#pragma unroll
    for (int j = 0; j < 8; ++j) {
      float nn = (float)(ee[j] & 0x7FFFu) * qs;
      f32x2 lo = __builtin_amdgcn_cvt_pk_f32_fp8((int)vv[j], false);
      f32x2 hi = __builtin_amdgcn_cvt_pk_f32_fp8((int)vv[j], true);
      a0 += nn * lo[0]; a1 += nn * lo[1]; a2 += nn * hi[0]; a3 += nn * hi[1];
    }
  }
  for (; i + 8 <= t; i += 8) {           // 4 edges per lane-parity
    uint ee[4];
#pragma unroll
    for (int j = 0; j < 4; ++j) ee[j] = csr[i + 2 * j + par];
    uint vv[4];
#pragma unroll
    for (int j = 0; j < 4; ++j) vv[j] = xw[(size_t)(ee[j] >> 15) * 32 + hl];
#pragma unroll
    for (int j = 0; j < 4; ++j) {
      float nn = (float)(ee[j] & 0x7FFFu) * qs;
      f32x2 lo = __builtin_amdgcn_cvt_pk_f32_fp8((int)vv[j], false);
      f32x2 hi = __builtin_amdgcn_cvt_pk_f32_fp8((int)vv[j], true);
      a0 += nn * lo[0]; a1 += nn * lo[1]; a2 += nn * hi[0]; a3 += nn * hi[1];
    }
  }
  for (; i < t; i += 2) {                // tail: up to 1 edge per parity
    if (i + par < t) {
      uint e = csr[i + par];
      uint v = xw[(size_t)(e >> 15) * 32 + hl];
      float nn = (float)(e & 0x7FFFu) * qs;
      f32x2 lo = __builtin_amdgcn_cvt_pk_f32_fp8((int)v, false);
      f32x2 hi = __builtin_amdgcn_cvt_pk_f32_fp8((int)v, true);
      a0 += nn * lo[0]; a1 += nn * lo[1]; a2 += nn * hi[0]; a3 += nn * hi[1];
    }
  }
  a0 += __shfl_xor(a0, 32);
  a1 += __shfl_xor(a1, 32);
  a2 += __shfl_xor(a2, 32);
  a3 += __shfl_xor(a3, 32);
  if (par == 0) {
    float4 b = *(const float4*)(bias + hl * 4);
    a0 = fmaxf(dc * a0 + b.x, 0.0f);
    a1 = fmaxf(dc * a1 + b.y, 0.0f);
    a2 = fmaxf(dc * a2 + b.z, 0.0f);
    a3 = fmaxf(dc * a3 + b.w, 0.0f);
    __half2 p0 = __floats2half2_rn(a0, a1);
    __half2 p1 = __floats2half2_rn(a2, a3);
    ((uint2*)out)[(size_t)node * 32 + hl] = make_uint2(*(uint*)&p0, *(uint*)&p1);
  }
}

// K5: fused mean-pool (sorted batch segments) + linear head.
// 256 threads: 4 row-groups x 64 feature-pair lanes; LDS reduce; wave 0
// computes out[g][0..1] via shfl reduction.
__global__ __launch_bounds__(256) void pool_final_kernel(
    const uint* __restrict__ h, const int* __restrict__ start,
    const float* __restrict__ Wl, const float* __restrict__ bl,
    float* __restrict__ out) {
  __shared__ float2 red[256];
  int g = blockIdx.x;
  int grp = threadIdx.x >> 6, f = threadIdx.x & 63;
  int s = start[g], e = start[g + 1];
  float s0 = 0.0f, s1 = 0.0f;
  for (int r = s + grp; r < e; r += 4) {
    uint v = h[((size_t)r << 6) + f];
    float2 fv = __half22float2(*(const __half2*)&v);
    s0 += fv.x;
    s1 += fv.y;
  }
  red[threadIdx.x] = make_float2(s0, s1);
  __syncthreads();
  if (grp == 0) {
    float2 a = red[f], b = red[64 + f], c = red[128 + f], d = red[192 + f];
    float inv = 1.0f / (float)max(e - s, 1);
    float pv0 = (a.x + b.x + c.x + d.x) * inv;   // feature 2f
    float pv1 = (a.y + b.y + c.y + d.y) * inv;   // feature 2f+1
#pragma unroll
    for (int o = 0; o < 2; ++o) {
      float sdot = pv0 * Wl[4 * f + o] + pv1 * Wl[4 * f + 2 + o];
      for (int d2 = 32; d2 > 0; d2 >>= 1) sdot += __shfl_down(sdot, d2);
      if (f == 0) out[g * 2 + o] = sdot + bl[o];
    }
  }
}

extern "C" void kernel_launch(void* const* d_in, const int* in_sizes, int n_in,
                              void* d_out, int out_size, void* d_ws, size_t ws_size,
                              hipStream_t stream) {
  const float* x     = (const float*)d_in[0];
  const int*   ei    = (const int*)d_in[1];
  const float* ew    = (const float*)d_in[2];
  const int*   batch = (const int*)d_in[3];
  const float* W1    = (const float*)d_in[4];
  const float* b1    = (const float*)d_in[5];
  const float* W2    = (const float*)d_in[6];
  const float* b2    = (const float*)d_in[7];
  const float* Wl    = (const float*)d_in[8];
  const float* bl    = (const float*)d_in[9];
  float* out = (float*)d_out;

  const int N = in_sizes[0] / HDIM;     // 100000
  const int E = in_sizes[2];            // 1600000
  const int G = out_size / 2;           // 512

  const int* row = ei;
  const int* col = ei + E;

  // ---- workspace layout (256B aligned) ----
  auto al = [](size_t v) { return (v + 255) & ~(size_t)255; };
  char* ws = (char*)d_ws;
  size_t o_dc32   = 0;                                   // u32[N] @16B stride (zeroed)
  size_t o_desc   = o_dc32   + al((size_t)N * 16);       // u64[512] lookback (zeroed)
  size_t zero_end = o_desc   + al(4096);
  size_t o_rank   = zero_end;                            // u8[E]
  size_t o_dis    = o_rank   + al((size_t)E);            // f32[N]
  size_t o_start  = o_dis    + al((size_t)N * 4);        // i32[G+1]
  size_t o_off    = o_start  + al(((size_t)G + 1) * 4);  // i32[N+1]
  size_t o_csr    = o_off    + al(((size_t)N + 1) * 4);  // u32[E]
  size_t o_xw     = o_csr    + al((size_t)E * 4);        // fp8 u8[N*128]
  size_t o_h      = o_xw     + al((size_t)N * 128);      // fp16x2 uint[N*64]

  uint*  dc32    = (uint*) (ws + o_dc32);
  u64*   desc    = (u64*)  (ws + o_desc);
  unsigned char* rank = (unsigned char*)(ws + o_rank);
  float* dis     = (float*)(ws + o_dis);
  int*   start   = (int*)  (ws + o_start);
  int*   off     = (int*)  (ws + o_off);
  uint*  csr     = (uint*) (ws + o_csr);
  unsigned char* xw = (unsigned char*)(ws + o_xw);
  uint*  hbuf    = (uint*) (ws + o_h);

  hipMemsetAsync(ws, 0, zero_end, stream);

  int EB = (E + 255) / 256;
  int NB = (N + 255) / 256;
  int nstrip = (N + 15) / 16;
  int MBg = 1024;             // gemm blocks in fused kernel (odd bids)
  int HB  = 1024;             // hist blocks (even bids, 4-deep atomic ILP)
  int MB  = 1024;             // gemm2 blocks
  int AB  = (N + 3) / 4;      // agg blocks (4 waves/block)

  // hist (atomic-bound) || gemm1 (MFMA/BW-bound), roles interleaved by parity
  gemm1_hist_kernel<<<MBg + HB, 256, 0, stream>>>(
      x, W1, xw, N, nstrip, MBg, col, ew, dc32, rank, E, HB);

  // dis + graph starts + full exclusive scan (decoupled lookback), one kernel
  node_scan_kernel<<<NB, 256, 0, stream>>>(dc32, dis, batch, start, off, desc,
                                           N, G, E);

  fill_kernel<<<EB, 256, 0, stream>>>(row, col, ew, rank, dis, off, csr, E);

  // layer 1 aggregate (fp8 gather -> fp16 h1)
  agg_kernel<<<AB, 256, 0, stream>>>((const uint*)xw, csr, dis, off, b1, hbuf, N);

  // layer 2: xw2 = fp8(h1 @ W2) ; h2 = fp16(relu(agg(xw2) + b2))
  gemm_mfma_kernel<<<MB, 256, 0, stream>>>((const _Float16*)hbuf, W2, xw, N, nstrip);
  agg_kernel<<<AB, 256, 0, stream>>>((const uint*)xw, csr, dis, off, b2, hbuf, N);

  // fused mean-pool + linear head
  pool_final_kernel<<<G, 256, 0, stream>>>(hbuf, start, Wl, bl, out);
}